// Round 1
// baseline (2163.626 us; speedup 1.0000x reference)
//
#include <hip/hip_runtime.h>

static constexpr int N = 512;    // state size == feature size
static constexpr int L = 16384;  // sequence length

// ---------------- elementwise helpers ----------------

__global__ void k_scale(const float* __restrict__ A, float* __restrict__ M, float h, int n) {
    int i = blockIdx.x * 256 + threadIdx.x;
    if (i < n) M[i] = A[i] * h;
}

// Ab = I + 2(M + M^2),  BL = I + M + M^2   (Neumann series, ||M|| ~ 1e-4)
__global__ void k_build(const float* __restrict__ M, const float* __restrict__ M2,
                        float* __restrict__ Ab, float* __restrict__ BL) {
    int i = blockIdx.x * 256 + threadIdx.x;
    if (i >= N * N) return;
    int r = i >> 9, c = i & (N - 1);
    float id = (r == c) ? 1.0f : 0.0f;
    float m = M[i], m2 = M2[i];
    Ab[i] = id + 2.0f * (m + m2);
    BL[i] = id + m + m2;
}

// 512x512 transpose
__global__ void k_transpose(const float* __restrict__ in, float* __restrict__ out) {
    __shared__ float t[32][33];
    int bx = blockIdx.x * 32, by = blockIdx.y * 32;
    int tx = threadIdx.x, ty = threadIdx.y;  // block 32x8
#pragma unroll
    for (int j = 0; j < 32; j += 8) t[ty + j][tx] = in[(by + ty + j) * N + bx + tx];
    __syncthreads();
#pragma unroll
    for (int j = 0; j < 32; j += 8) out[(bx + ty + j) * N + by + tx] = t[tx][ty + j];
}

// ---------------- NT GEMM, 128x128 tile (for L-row ops) ----------------
// OUT[i,j] = (ADD ? Xadd[i,j] : 0) + scale * sum_k Asrc[i-shift, k] * Bmat[j, k]
// rows with i-shift < 0 contribute 0. Row count = gridDim.x*128, cols = 512, K = 512.
template <bool ADD>
__global__ __launch_bounds__(256) void k_gemm_nt128(
    const float* __restrict__ Asrc, const float* __restrict__ Bmat,
    const float* __restrict__ Xadd, float* __restrict__ OUT, int shift, float scale) {
    __shared__ float As[16][128];
    __shared__ float Bs[16][128];
    const int tid = threadIdx.x;
    const long brow = (long)blockIdx.x * 128;
    const int bcol = blockIdx.y * 128;
    const int tx = tid & 15, ty = tid >> 4;
    float acc[8][8] = {};

    for (int k0 = 0; k0 < N; k0 += 16) {
#pragma unroll
        for (int q = 0; q < 2; ++q) {
            int idx = tid * 2 + q;      // 0..511
            int row = idx >> 2;         // 0..127
            int kq = (idx & 3) << 2;    // 0,4,8,12
            long gr = brow + row - shift;
            float4 va = make_float4(0.f, 0.f, 0.f, 0.f);
            if (gr >= 0) va = *(const float4*)(Asrc + gr * N + k0 + kq);
            As[kq + 0][row] = va.x; As[kq + 1][row] = va.y;
            As[kq + 2][row] = va.z; As[kq + 3][row] = va.w;
            float4 vb = *(const float4*)(Bmat + (long)(bcol + row) * N + k0 + kq);
            Bs[kq + 0][row] = vb.x; Bs[kq + 1][row] = vb.y;
            Bs[kq + 2][row] = vb.z; Bs[kq + 3][row] = vb.w;
        }
        __syncthreads();
#pragma unroll
        for (int kk = 0; kk < 16; ++kk) {
            float a[8], b[8];
            *(float4*)&a[0] = *(const float4*)&As[kk][ty * 8];
            *(float4*)&a[4] = *(const float4*)&As[kk][ty * 8 + 4];
            *(float4*)&b[0] = *(const float4*)&Bs[kk][tx * 8];
            *(float4*)&b[4] = *(const float4*)&Bs[kk][tx * 8 + 4];
#pragma unroll
            for (int i = 0; i < 8; ++i)
#pragma unroll
                for (int j = 0; j < 8; ++j) acc[i][j] = fmaf(a[i], b[j], acc[i][j]);
        }
        __syncthreads();
    }

#pragma unroll
    for (int i = 0; i < 8; ++i) {
        long gi = brow + ty * 8 + i;
        float* orow = OUT + gi * N + bcol + tx * 8;
        const float* xrow = Xadd + gi * N + bcol + tx * 8;
#pragma unroll
        for (int j = 0; j < 8; j += 4) {
            float4 o;
            o.x = scale * acc[i][j + 0]; o.y = scale * acc[i][j + 1];
            o.z = scale * acc[i][j + 2]; o.w = scale * acc[i][j + 3];
            if (ADD) {
                float4 x = *(const float4*)(xrow + j);
                o.x += x.x; o.y += x.y; o.z += x.z; o.w += x.w;
            }
            *(float4*)(orow + j) = o;
        }
    }
}

// ---------------- NT GEMM, 64x64 tile (for 512^3 builds/squarings) ----------------
// OUT[i,j] = scale * sum_k Asrc[i,k] * Bmat[j,k]
__global__ __launch_bounds__(256) void k_gemm_nt64(
    const float* __restrict__ Asrc, const float* __restrict__ Bmat,
    float* __restrict__ OUT, float scale) {
    __shared__ float As[32][64];
    __shared__ float Bs[32][64];
    const int tid = threadIdx.x;
    const int brow = blockIdx.x * 64;
    const int bcol = blockIdx.y * 64;
    const int tx = tid & 15, ty = tid >> 4;
    float acc[4][4] = {};

    for (int k0 = 0; k0 < N; k0 += 32) {
#pragma unroll
        for (int q = 0; q < 2; ++q) {
            int idx = tid * 2 + q;      // 0..511
            int row = idx >> 3;         // 0..63
            int kq = (idx & 7) << 2;    // 0..28
            float4 va = *(const float4*)(Asrc + (long)(brow + row) * N + k0 + kq);
            As[kq + 0][row] = va.x; As[kq + 1][row] = va.y;
            As[kq + 2][row] = va.z; As[kq + 3][row] = va.w;
            float4 vb = *(const float4*)(Bmat + (long)(bcol + row) * N + k0 + kq);
            Bs[kq + 0][row] = vb.x; Bs[kq + 1][row] = vb.y;
            Bs[kq + 2][row] = vb.z; Bs[kq + 3][row] = vb.w;
        }
        __syncthreads();
#pragma unroll
        for (int kk = 0; kk < 32; ++kk) {
            float a[4], b[4];
            *(float4*)&a[0] = *(const float4*)&As[kk][ty * 4];
            *(float4*)&b[0] = *(const float4*)&Bs[kk][tx * 4];
#pragma unroll
            for (int i = 0; i < 4; ++i)
#pragma unroll
                for (int j = 0; j < 4; ++j) acc[i][j] = fmaf(a[i], b[j], acc[i][j]);
        }
        __syncthreads();
    }

#pragma unroll
    for (int i = 0; i < 4; ++i) {
        float* orow = OUT + (long)(brow + ty * 4 + i) * N + bcol + tx * 4;
        float4 o;
        o.x = scale * acc[i][0]; o.y = scale * acc[i][1];
        o.z = scale * acc[i][2]; o.w = scale * acc[i][3];
        *(float4*)orow = o;
    }
}

// ---------------- launcher ----------------

extern "C" void kernel_launch(void* const* d_in, const int* in_sizes, int n_in,
                              void* d_out, int out_size, void* d_ws, size_t ws_size,
                              hipStream_t stream) {
    (void)in_sizes; (void)n_in; (void)out_size; (void)ws_size;
    const float* A = (const float*)d_in[0];
    const float* B = (const float*)d_in[1];
    const float* C = (const float*)d_in[2];
    const float* u = (const float*)d_in[3];

    float* X1 = (float*)d_out;          // ping-pong buffer #2 (overwritten at the end)
    float* ws = (float*)d_ws;
    float* X0 = ws;                     // L*N floats = 32 MB
    float* mats = ws + (size_t)L * N;
    float* M   = mats + 0 * (size_t)N * N;
    float* MT  = mats + 1 * (size_t)N * N;
    float* M2  = mats + 2 * (size_t)N * N;
    float* BL  = mats + 3 * (size_t)N * N;
    float* BT  = mats + 4 * (size_t)N * N;
    float* Bb  = mats + 5 * (size_t)N * N;
    float* Qa  = mats + 6 * (size_t)N * N;
    float* QTa = mats + 7 * (size_t)N * N;
    float* Qb  = mats + 8 * (size_t)N * N;

    const float step = 1.0f / (float)L;

    dim3 b256(256);
    dim3 gEl((N * N + 255) / 256);
    dim3 bT(32, 8), gT(N / 32, N / 32);
    dim3 g64(N / 64, N / 64);
    dim3 gBig(L / 128, N / 128);

    // M = A * (step/2); M2 = M @ M
    k_scale<<<gEl, b256, 0, stream>>>(A, M, step * 0.5f, N * N);
    k_transpose<<<gT, bT, 0, stream>>>(M, MT);
    k_gemm_nt64<<<g64, b256, 0, stream>>>(M, MT, M2, 1.0f);   // M2 = M*MT^T = M*M
    // Ab (-> Qa), BL
    k_build<<<gEl, b256, 0, stream>>>(M, M2, Qa, BL);
    k_transpose<<<gT, bT, 0, stream>>>(Qa, QTa);
    // Bb = step * BL @ B
    k_transpose<<<gT, bT, 0, stream>>>(B, BT);
    k_gemm_nt64<<<g64, b256, 0, stream>>>(BL, BT, Bb, step);
    // X0 = Bu = u @ Bb^T
    k_gemm_nt128<false><<<gBig, b256, 0, stream>>>(u, Bb, nullptr, X0, 0, 1.0f);

    // 14 doubling rounds: X[i] += Ab^(2^r) @ X[i - 2^r]
    float* Q = Qa; float* QT = QTa; float* Qs = Qb;
    for (int r = 0; r < 14; ++r) {
        float* Xin  = (r & 1) ? X1 : X0;
        float* Xout = (r & 1) ? X0 : X1;
        k_gemm_nt128<true><<<gBig, b256, 0, stream>>>(Xin, Q, Xin, Xout, 1 << r, 1.0f);
        if (r < 13) {
            k_gemm_nt64<<<g64, b256, 0, stream>>>(Q, QT, Qs, 1.0f);  // Qs = Q@Q
            k_transpose<<<gT, bT, 0, stream>>>(Qs, QT);
            float* t = Q; Q = Qs; Qs = t;
        }
    }
    // after 14 rounds (even count) X lives in X0; final: OUT = X @ C^T
    k_gemm_nt128<false><<<gBig, b256, 0, stream>>>(X0, C, nullptr, X1, 0, 1.0f);
}

// Round 2
// 956.988 us; speedup vs baseline: 2.2609x; 2.2609x over previous
//
#include <hip/hip_runtime.h>
#include <hip/hip_bf16.h>

static constexpr int N = 512;    // state size == feature size
static constexpr int L = 16384;  // sequence length

typedef short s16x8 __attribute__((ext_vector_type(8)));
typedef float f32x4 __attribute__((ext_vector_type(4)));
using bf16 = __hip_bfloat16;

#define GPTR(p) ((const __attribute__((address_space(1))) void*)(p))
#define LPTR(p) ((__attribute__((address_space(3))) void*)(p))

__device__ __forceinline__ void gload16(const void* g, void* l) {
    __builtin_amdgcn_global_load_lds(GPTR(g), LPTR(l), 16, 0, 0);
}

// ---------------- elementwise helpers ----------------

__global__ void k_scale(const float* __restrict__ A, float* __restrict__ M, float h, int n) {
    int i = blockIdx.x * 256 + threadIdx.x;
    if (i < n) M[i] = A[i] * h;
}

__global__ void k_build(const float* __restrict__ M, const float* __restrict__ M2,
                        float* __restrict__ Ab, float* __restrict__ BL) {
    int i = blockIdx.x * 256 + threadIdx.x;
    if (i >= N * N) return;
    int r = i >> 9, c = i & (N - 1);
    float id = (r == c) ? 1.0f : 0.0f;
    float m = M[i], m2 = M2[i];
    Ab[i] = id + 2.0f * (m + m2);
    BL[i] = id + m + m2;
}

__global__ void k_zeroinit(int* zb) { zb[threadIdx.x] = 0; }  // 256 ints = 1KB zeros

// f32 -> (hi, lo) bf16 split
__global__ void k_split(const float* __restrict__ in, bf16* __restrict__ hi,
                        bf16* __restrict__ lo, int n) {
    int i = blockIdx.x * 256 + threadIdx.x;
    if (i >= n) return;
    float v = in[i];
    bf16 h = __float2bfloat16(v);
    hi[i] = h;
    lo[i] = __float2bfloat16(v - __bfloat162float(h));
}

// 512x512 transpose
__global__ void k_transpose(const float* __restrict__ in, float* __restrict__ out) {
    __shared__ float t[32][33];
    int bx = blockIdx.x * 32, by = blockIdx.y * 32;
    int tx = threadIdx.x, ty = threadIdx.y;  // block 32x8
#pragma unroll
    for (int j = 0; j < 32; j += 8) t[ty + j][tx] = in[(by + ty + j) * N + bx + tx];
    __syncthreads();
#pragma unroll
    for (int j = 0; j < 32; j += 8) out[(bx + ty + j) * N + by + tx] = t[tx][ty + j];
}

// ---------------- f32 NT GEMM, 64x64 tile (512^3 squaring chain) ----------------
__global__ __launch_bounds__(256) void k_gemm_nt64(
    const float* __restrict__ Asrc, const float* __restrict__ Bmat,
    float* __restrict__ OUT, float scale) {
    __shared__ float As[32][64];
    __shared__ float Bs[32][64];
    const int tid = threadIdx.x;
    const int brow = blockIdx.x * 64;
    const int bcol = blockIdx.y * 64;
    const int tx = tid & 15, ty = tid >> 4;
    float acc[4][4] = {};

    for (int k0 = 0; k0 < N; k0 += 32) {
#pragma unroll
        for (int q = 0; q < 2; ++q) {
            int idx = tid * 2 + q;
            int row = idx >> 3;
            int kq = (idx & 7) << 2;
            float4 va = *(const float4*)(Asrc + (long)(brow + row) * N + k0 + kq);
            As[kq + 0][row] = va.x; As[kq + 1][row] = va.y;
            As[kq + 2][row] = va.z; As[kq + 3][row] = va.w;
            float4 vb = *(const float4*)(Bmat + (long)(bcol + row) * N + k0 + kq);
            Bs[kq + 0][row] = vb.x; Bs[kq + 1][row] = vb.y;
            Bs[kq + 2][row] = vb.z; Bs[kq + 3][row] = vb.w;
        }
        __syncthreads();
#pragma unroll
        for (int kk = 0; kk < 32; ++kk) {
            float a[4], b[4];
            *(float4*)&a[0] = *(const float4*)&As[kk][ty * 4];
            *(float4*)&b[0] = *(const float4*)&Bs[kk][tx * 4];
#pragma unroll
            for (int i = 0; i < 4; ++i)
#pragma unroll
                for (int j = 0; j < 4; ++j) acc[i][j] = fmaf(a[i], b[j], acc[i][j]);
        }
        __syncthreads();
    }
#pragma unroll
    for (int i = 0; i < 4; ++i) {
        float* orow = OUT + (long)(brow + ty * 4 + i) * N + bcol + tx * 4;
        float4 o;
        o.x = scale * acc[i][0]; o.y = scale * acc[i][1];
        o.z = scale * acc[i][2]; o.w = scale * acc[i][3];
        *(float4*)orow = o;
    }
}

// ---------------- bf16x3 MFMA NT GEMM, 128x128 tile ----------------
// OUT[i,j] = (ADD ? Xa[i,j] : 0) + sum_k Ain[i-shift,k] * Bin[j,k]
// A, B, Xa given as (hi,lo) bf16 pairs; rows i-shift<0 read zeros (zb redirect).
// OUTF32: write f32 to Of; else split result into (Oh, Ol) bf16 pair.
template <bool ADD, bool OUTF32>
__global__ __launch_bounds__(256, 2) void k_bigmm(
    const bf16* __restrict__ Ah, const bf16* __restrict__ Al,
    const bf16* __restrict__ Bh, const bf16* __restrict__ Bl,
    const bf16* __restrict__ Xah, const bf16* __restrict__ Xal,
    bf16* __restrict__ Oh, bf16* __restrict__ Ol, float* __restrict__ Of,
    int shift, const bf16* __restrict__ zb)
{
    // LDS: A_hi [0,8K) A_lo [8,16K) B_hi [16,24K) B_lo [24,32K); each 128 rows x 32 k bf16
    __shared__ char smem[32768];
    const int tid = threadIdx.x;
    const int wave = tid >> 6, lane = tid & 63;
    const long brow = (long)blockIdx.x * 128;
    const int bcol = blockIdx.y * 128;
    const int wm = wave >> 1, wn = wave & 1;   // 2x2 wave grid, 64x64 per wave

    f32x4 acc[4][4];
#pragma unroll
    for (int m = 0; m < 4; ++m)
#pragma unroll
        for (int n = 0; n < 4; ++n) acc[m][n] = (f32x4){0.f, 0.f, 0.f, 0.f};

    // staging pointers: idx = q*256+tid; row=idx>>2, slot=idx&3, swz slot' = slot^((row>>1)&3)
    const char* pAh[2]; const char* pAl[2]; const char* pBh[2]; const char* pBl[2];
    int wb[2];
#pragma unroll
    for (int q = 0; q < 2; ++q) {
        int idx = q * 256 + tid;
        int row = idx >> 2, slot = idx & 3;
        int sp = slot ^ ((row >> 1) & 3);
        long gra = brow + row - shift;
        pAh[q] = (gra >= 0) ? (const char*)(Ah + gra * N + sp * 8) : (const char*)(zb + sp * 8);
        pAl[q] = (gra >= 0) ? (const char*)(Al + gra * N + sp * 8) : (const char*)(zb + sp * 8);
        long eb = (long)(bcol + row) * N + sp * 8;
        pBh[q] = (const char*)(Bh + eb);
        pBl[q] = (const char*)(Bl + eb);
        wb[q] = (q * 256 + wave * 64) * 16;
    }

    const int slot = lane >> 4;   // k-chunk of 8 within BK=32
    const int rl = lane & 15;

    for (int k0 = 0; k0 < N; k0 += 32) {
        const int kb = k0 * 2;  // byte advance in global rows
#pragma unroll
        for (int q = 0; q < 2; ++q) {
            gload16(pAh[q] + kb, smem + 0     + wb[q]);
            gload16(pAl[q] + kb, smem + 8192  + wb[q]);
            gload16(pBh[q] + kb, smem + 16384 + wb[q]);
            gload16(pBl[q] + kb, smem + 24576 + wb[q]);
        }
        __syncthreads();   // compiler drains vmcnt before barrier

        s16x8 ah[4], al[4], bh[4], bl[4];
#pragma unroll
        for (int m = 0; m < 4; ++m) {
            int row = wm * 64 + m * 16 + rl;
            int off = row * 64 + (slot ^ ((row >> 1) & 3)) * 16;
            ah[m] = *reinterpret_cast<const s16x8*>(smem + off);
            al[m] = *reinterpret_cast<const s16x8*>(smem + 8192 + off);
        }
#pragma unroll
        for (int n = 0; n < 4; ++n) {
            int row = wn * 64 + n * 16 + rl;
            int off = row * 64 + (slot ^ ((row >> 1) & 3)) * 16;
            bh[n] = *reinterpret_cast<const s16x8*>(smem + 16384 + off);
            bl[n] = *reinterpret_cast<const s16x8*>(smem + 24576 + off);
        }
#pragma unroll
        for (int m = 0; m < 4; ++m)
#pragma unroll
            for (int n = 0; n < 4; ++n) {
                acc[m][n] = __builtin_amdgcn_mfma_f32_16x16x32_bf16(ah[m], bh[n], acc[m][n], 0, 0, 0);
                acc[m][n] = __builtin_amdgcn_mfma_f32_16x16x32_bf16(ah[m], bl[n], acc[m][n], 0, 0, 0);
                acc[m][n] = __builtin_amdgcn_mfma_f32_16x16x32_bf16(al[m], bh[n], acc[m][n], 0, 0, 0);
            }
        __syncthreads();
    }

    // epilogue: C/D layout col=lane&15, row=(lane>>4)*4+reg  [m89/m91]
    const int rh = lane >> 4;
    const long orow0 = brow + wm * 64;
    const int ocol0 = bcol + wn * 64;
#pragma unroll
    for (int m = 0; m < 4; ++m) {
#pragma unroll
        for (int r = 0; r < 4; ++r) {
            long row = orow0 + m * 16 + rh * 4 + r;
            long base = row * N + ocol0 + rl;
#pragma unroll
            for (int n = 0; n < 4; ++n) {
                float v = acc[m][n][r];
                long off = base + n * 16;
                if (ADD) v += __bfloat162float(Xah[off]) + __bfloat162float(Xal[off]);
                if (OUTF32) {
                    Of[off] = v;
                } else {
                    bf16 h = __float2bfloat16(v);
                    Oh[off] = h;
                    Ol[off] = __float2bfloat16(v - __bfloat162float(h));
                }
            }
        }
    }
}

// ---------------- launcher ----------------

extern "C" void kernel_launch(void* const* d_in, const int* in_sizes, int n_in,
                              void* d_out, int out_size, void* d_ws, size_t ws_size,
                              hipStream_t stream) {
    (void)in_sizes; (void)n_in; (void)out_size; (void)ws_size;
    const float* A = (const float*)d_in[0];
    const float* B = (const float*)d_in[1];
    const float* C = (const float*)d_in[2];
    const float* u = (const float*)d_in[3];

    // X1 pair lives in d_out (2 * 16MB bf16 == 32MB f32 out buffer)
    bf16* X1h = (bf16*)d_out;
    bf16* X1l = X1h + (size_t)L * N;

    char* w = (char*)d_ws;
    bf16* X0h = (bf16*)w;                w += (size_t)L * N * 2;
    bf16* X0l = (bf16*)w;                w += (size_t)L * N * 2;
    float* M   = (float*)w;              w += (size_t)N * N * 4;
    float* MT  = (float*)w;              w += (size_t)N * N * 4;
    float* M2  = (float*)w;              w += (size_t)N * N * 4;
    float* BLm = (float*)w;              w += (size_t)N * N * 4;
    float* BT  = (float*)w;              w += (size_t)N * N * 4;
    float* Bbf = (float*)w;              w += (size_t)N * N * 4;
    float* Qa  = (float*)w;              w += (size_t)N * N * 4;
    float* QTa = (float*)w;              w += (size_t)N * N * 4;
    float* Qb  = (float*)w;              w += (size_t)N * N * 4;
    bf16* Qh   = (bf16*)w;               w += (size_t)N * N * 2;
    bf16* Ql   = (bf16*)w;               w += (size_t)N * N * 2;
    bf16* Bbh  = (bf16*)w;               w += (size_t)N * N * 2;
    bf16* Bbl  = (bf16*)w;               w += (size_t)N * N * 2;
    bf16* Ch   = (bf16*)w;               w += (size_t)N * N * 2;
    bf16* Cl   = (bf16*)w;               w += (size_t)N * N * 2;
    bf16* zb   = (bf16*)w;               w += 1024;

    const float step = 1.0f / (float)L;

    dim3 b256(256);
    dim3 gEl((N * N + 255) / 256);
    dim3 gSplitNN((N * N + 255) / 256);
    dim3 gSplitLN((L * N + 255) / 256);
    dim3 bT(32, 8), gT(N / 32, N / 32);
    dim3 g64(N / 64, N / 64);
    dim3 gBig(L / 128, N / 128);

    k_zeroinit<<<1, 256, 0, stream>>>((int*)zb);

    // M = A*(step/2); M2 = M@M; Ab(->Qa), BL; Bb = step*BL@B
    k_scale<<<gEl, b256, 0, stream>>>(A, M, step * 0.5f, N * N);
    k_transpose<<<gT, bT, 0, stream>>>(M, MT);
    k_gemm_nt64<<<g64, b256, 0, stream>>>(M, MT, M2, 1.0f);
    k_build<<<gEl, b256, 0, stream>>>(M, M2, Qa, BLm);
    k_transpose<<<gT, bT, 0, stream>>>(B, BT);
    k_gemm_nt64<<<g64, b256, 0, stream>>>(BLm, BT, Bbf, step);

    // splits
    k_split<<<gSplitNN, b256, 0, stream>>>(Bbf, Bbh, Bbl, N * N);
    k_split<<<gSplitNN, b256, 0, stream>>>(C, Ch, Cl, N * N);
    k_split<<<gSplitLN, b256, 0, stream>>>(u, X1h, X1l, L * N);  // u split in X1/d_out

    // X0 = Bu = u @ Bb^T
    k_bigmm<false, false><<<gBig, b256, 0, stream>>>(
        X1h, X1l, Bbh, Bbl, nullptr, nullptr, X0h, X0l, nullptr, 0, zb);

    // doubling rounds: X[i] += Ab^(2^r) @ X[i - 2^r]
    k_transpose<<<gT, bT, 0, stream>>>(Qa, QTa);
    float* Qc = Qa; float* Qn = Qb;
    for (int r = 0; r < 14; ++r) {
        k_split<<<gSplitNN, b256, 0, stream>>>(Qc, Qh, Ql, N * N);
        bf16* Xih = (r & 1) ? X1h : X0h;  bf16* Xil = (r & 1) ? X1l : X0l;
        bf16* Xoh = (r & 1) ? X0h : X1h;  bf16* Xol = (r & 1) ? X0l : X1l;
        k_bigmm<true, false><<<gBig, b256, 0, stream>>>(
            Xih, Xil, Qh, Ql, Xih, Xil, Xoh, Xol, nullptr, 1 << r, zb);
        if (r < 13) {
            k_gemm_nt64<<<g64, b256, 0, stream>>>(Qc, QTa, Qn, 1.0f);  // Qn = Qc^2
            k_transpose<<<gT, bT, 0, stream>>>(Qn, QTa);
            float* t = Qc; Qc = Qn; Qn = t;
        }
    }

    // final: OUT = X0 @ C^T (f32)
    k_bigmm<false, true><<<gBig, b256, 0, stream>>>(
        X0h, X0l, Ch, Cl, nullptr, nullptr, nullptr, nullptr, (float*)d_out, 0, zb);
}

// Round 3
// 886.044 us; speedup vs baseline: 2.4419x; 1.0801x over previous
//
#include <hip/hip_runtime.h>
#include <hip/hip_bf16.h>

static constexpr int N = 512;    // state size == feature size
static constexpr int L = 16384;  // sequence length

typedef short s16x8 __attribute__((ext_vector_type(8)));
typedef float f32x4 __attribute__((ext_vector_type(4)));
using bf16 = __hip_bfloat16;

#define GPTR(p) ((const __attribute__((address_space(1))) void*)(p))
#define LPTR(p) ((__attribute__((address_space(3))) void*)(p))

__device__ __forceinline__ void gload16(const void* g, void* l) {
    __builtin_amdgcn_global_load_lds(GPTR(g), LPTR(l), 16, 0, 0);
}

__device__ __forceinline__ void split2(float v, ushort& h, ushort& l) {
    bf16 hb = __float2bfloat16(v);
    h = *reinterpret_cast<ushort*>(&hb);
    bf16 lb = __float2bfloat16(v - __bfloat162float(hb));
    l = *reinterpret_cast<ushort*>(&lb);
}

// ---------------- elementwise helpers ----------------

__global__ void k_scale(const float* __restrict__ A, float* __restrict__ M, float h, int n) {
    int i = blockIdx.x * 256 + threadIdx.x;
    if (i < n) M[i] = A[i] * h;
}

// Ab = I + 2(M + M^2) -> f32 + bf16 split;  BL = I + M + M^2
__global__ void k_build(const float* __restrict__ M, const float* __restrict__ M2,
                        float* __restrict__ Ab, float* __restrict__ BL,
                        bf16* __restrict__ Abh, bf16* __restrict__ Abl) {
    int i = blockIdx.x * 256 + threadIdx.x;
    if (i >= N * N) return;
    int r = i >> 9, c = i & (N - 1);
    float id = (r == c) ? 1.0f : 0.0f;
    float m = M[i], m2 = M2[i];
    float ab = id + 2.0f * (m + m2);
    Ab[i] = ab;
    BL[i] = id + m + m2;
    ushort h, l;
    split2(ab, h, l);
    *reinterpret_cast<ushort*>(Abh + i) = h;
    *reinterpret_cast<ushort*>(Abl + i) = l;
}

__global__ void k_zeroinit(int* zb) { zb[threadIdx.x] = 0; }  // 1KB zeros

// vectorized f32 -> (hi, lo) bf16 split, 4 elems/thread
__global__ void k_split4(const float* __restrict__ in, bf16* __restrict__ hi,
                         bf16* __restrict__ lo, int n4) {
    int i = blockIdx.x * 256 + threadIdx.x;
    if (i >= n4) return;
    float4 v = reinterpret_cast<const float4*>(in)[i];
    ushort ht[4], lt[4];
    split2(v.x, ht[0], lt[0]);
    split2(v.y, ht[1], lt[1]);
    split2(v.z, ht[2], lt[2]);
    split2(v.w, ht[3], lt[3]);
    *reinterpret_cast<ushort4*>(hi + 4 * (size_t)i) = *reinterpret_cast<ushort4*>(ht);
    *reinterpret_cast<ushort4*>(lo + 4 * (size_t)i) = *reinterpret_cast<ushort4*>(lt);
}

// 512x512 transpose
__global__ void k_transpose(const float* __restrict__ in, float* __restrict__ out) {
    __shared__ float t[32][33];
    int bx = blockIdx.x * 32, by = blockIdx.y * 32;
    int tx = threadIdx.x, ty = threadIdx.y;  // block 32x8
#pragma unroll
    for (int j = 0; j < 32; j += 8) t[ty + j][tx] = in[(by + ty + j) * N + bx + tx];
    __syncthreads();
#pragma unroll
    for (int j = 0; j < 32; j += 8) out[(bx + ty + j) * N + by + tx] = t[tx][ty + j];
}

// ---------------- f32 NT GEMM 64x64 + fused {transpose, bf16-split} epilogue ----
// OUT = scale * Asrc @ Bmat^T ; optionally OUTT = OUT^T ; (Sh,Sl) = bf16 split of OUT
template <bool WRITE_T>
__global__ __launch_bounds__(256) void k_qsq(
    const float* __restrict__ Asrc, const float* __restrict__ Bmat,
    float* __restrict__ OUT, float* __restrict__ OUTT,
    bf16* __restrict__ Sh, bf16* __restrict__ Sl, float scale) {
    __shared__ float As[32][64];
    __shared__ float Bs[32][64];
    const int tid = threadIdx.x;
    const int brow = blockIdx.x * 64;
    const int bcol = blockIdx.y * 64;
    const int tx = tid & 15, ty = tid >> 4;
    float acc[4][4] = {};

    for (int k0 = 0; k0 < N; k0 += 32) {
#pragma unroll
        for (int q = 0; q < 2; ++q) {
            int idx = tid * 2 + q;
            int row = idx >> 3;
            int kq = (idx & 7) << 2;
            float4 va = *(const float4*)(Asrc + (long)(brow + row) * N + k0 + kq);
            As[kq + 0][row] = va.x; As[kq + 1][row] = va.y;
            As[kq + 2][row] = va.z; As[kq + 3][row] = va.w;
            float4 vb = *(const float4*)(Bmat + (long)(bcol + row) * N + k0 + kq);
            Bs[kq + 0][row] = vb.x; Bs[kq + 1][row] = vb.y;
            Bs[kq + 2][row] = vb.z; Bs[kq + 3][row] = vb.w;
        }
        __syncthreads();
#pragma unroll
        for (int kk = 0; kk < 32; ++kk) {
            float a[4], b[4];
            *(float4*)&a[0] = *(const float4*)&As[kk][ty * 4];
            *(float4*)&b[0] = *(const float4*)&Bs[kk][tx * 4];
#pragma unroll
            for (int i = 0; i < 4; ++i)
#pragma unroll
                for (int j = 0; j < 4; ++j) acc[i][j] = fmaf(a[i], b[j], acc[i][j]);
        }
        __syncthreads();
    }
#pragma unroll
    for (int i = 0; i < 4; ++i)
#pragma unroll
        for (int j = 0; j < 4; ++j) acc[i][j] *= scale;

#pragma unroll
    for (int i = 0; i < 4; ++i) {
        long off = (long)(brow + ty * 4 + i) * N + bcol + tx * 4;
        float4 o = make_float4(acc[i][0], acc[i][1], acc[i][2], acc[i][3]);
        *(float4*)(OUT + off) = o;
        ushort ht[4], lt[4];
        split2(o.x, ht[0], lt[0]); split2(o.y, ht[1], lt[1]);
        split2(o.z, ht[2], lt[2]); split2(o.w, ht[3], lt[3]);
        *reinterpret_cast<ushort4*>(Sh + off) = *reinterpret_cast<ushort4*>(ht);
        *reinterpret_cast<ushort4*>(Sl + off) = *reinterpret_cast<ushort4*>(lt);
    }
    if (WRITE_T) {
#pragma unroll
        for (int j = 0; j < 4; ++j) {
            long off = (long)(bcol + tx * 4 + j) * N + brow + ty * 4;
            float4 o = make_float4(acc[0][j], acc[1][j], acc[2][j], acc[3][j]);
            *(float4*)(OUTT + off) = o;
        }
    }
}

// ---------------- bf16x3 MFMA NT GEMM, 128x128 tile, double-buffered 2-phase ----
// OUT[i,j] = (ADD ? Xa[i,j] : 0) + sum_k Ain[i-shift,k] * Bin[j,k]
template <bool ADD, bool OUTF32>
__global__ __launch_bounds__(256, 2) void k_bigmm(
    const bf16* __restrict__ Ah, const bf16* __restrict__ Al,
    const bf16* __restrict__ Bh, const bf16* __restrict__ Bl,
    const bf16* __restrict__ Xah, const bf16* __restrict__ Xal,
    bf16* __restrict__ Oh, bf16* __restrict__ Ol, float* __restrict__ Of,
    int shift, const bf16* __restrict__ zb)
{
    const int tid = threadIdx.x;
    const long brow = (long)blockIdx.x * 128;
    const int bcol = blockIdx.y * 128;

    if (ADD && brow + 127 < (long)shift) {
        // whole tile below shift: OUT = Xadd (pure copy), skip GEMM
#pragma unroll
        for (int j = 0; j < 8; ++j) {
            int c = j * 256 + tid;
            long off = (brow + (c >> 4)) * N + bcol + (c & 15) * 8;
            *reinterpret_cast<int4*>(Oh + off) = *reinterpret_cast<const int4*>(Xah + off);
            *reinterpret_cast<int4*>(Ol + off) = *reinterpret_cast<const int4*>(Xal + off);
        }
        return;
    }

    // LDS: 2 buffers x { A_hi[0,8K) A_lo[8,16K) B_hi[16,24K) B_lo[24,32K) }
    __shared__ char smem[65536];
    const int wave = tid >> 6, lane = tid & 63;
    const int wm = wave >> 1, wn = wave & 1;   // 2x2 wave grid, 64x64 per wave

    f32x4 acc[4][4];
#pragma unroll
    for (int m = 0; m < 4; ++m)
#pragma unroll
        for (int n = 0; n < 4; ++n) acc[m][n] = (f32x4){0.f, 0.f, 0.f, 0.f};

    // staging: chunk idx = q*256+tid; row=idx>>2, slot=idx&3, swizzled slot' = slot^((row>>1)&3)
    const char* pAh[2]; const char* pAl[2]; const char* pBh[2]; const char* pBl[2];
    int wb[2];
#pragma unroll
    for (int q = 0; q < 2; ++q) {
        int idx = q * 256 + tid;
        int row = idx >> 2, slot = idx & 3;
        int sp = slot ^ ((row >> 1) & 3);
        long gra = brow + row - shift;
        pAh[q] = (gra >= 0) ? (const char*)(Ah + gra * N + sp * 8) : (const char*)(zb + sp * 8);
        pAl[q] = (gra >= 0) ? (const char*)(Al + gra * N + sp * 8) : (const char*)(zb + sp * 8);
        long eb = (long)(bcol + row) * N + sp * 8;
        pBh[q] = (const char*)(Bh + eb);
        pBl[q] = (const char*)(Bl + eb);
        wb[q] = (q * 256 + wave * 64) * 16;
    }

    const int slot = lane >> 4;   // 16B k-chunk within BK=32
    const int rl = lane & 15;

    // prologue: stage tile 0 into buf 0
#pragma unroll
    for (int q = 0; q < 2; ++q) {
        gload16(pAh[q], smem + 0     + wb[q]);
        gload16(pAl[q], smem + 8192  + wb[q]);
        gload16(pBh[q], smem + 16384 + wb[q]);
        gload16(pBl[q], smem + 24576 + wb[q]);
    }
    __syncthreads();

    int cur = 0;
    for (int t = 0; t < 16; ++t) {
        const char* base = smem + cur * 32768;
        // ds_read current fragments
        s16x8 ah[4], al[4], bh[4], bl[4];
#pragma unroll
        for (int m = 0; m < 4; ++m) {
            int row = wm * 64 + m * 16 + rl;
            int off = row * 64 + (slot ^ ((row >> 1) & 3)) * 16;
            ah[m] = *reinterpret_cast<const s16x8*>(base + off);
            al[m] = *reinterpret_cast<const s16x8*>(base + 8192 + off);
        }
#pragma unroll
        for (int n = 0; n < 4; ++n) {
            int row = wn * 64 + n * 16 + rl;
            int off = row * 64 + (slot ^ ((row >> 1) & 3)) * 16;
            bh[n] = *reinterpret_cast<const s16x8*>(base + 16384 + off);
            bl[n] = *reinterpret_cast<const s16x8*>(base + 24576 + off);
        }
        // stage next tile into the other buffer (hides under MFMA below)
        if (t + 1 < 16) {
            const int kb = (t + 1) * 64;  // 32 cols * 2B
            char* nb = smem + (cur ^ 1) * 32768;
#pragma unroll
            for (int q = 0; q < 2; ++q) {
                gload16(pAh[q] + kb, nb + 0     + wb[q]);
                gload16(pAl[q] + kb, nb + 8192  + wb[q]);
                gload16(pBh[q] + kb, nb + 16384 + wb[q]);
                gload16(pBl[q] + kb, nb + 24576 + wb[q]);
            }
        }
#pragma unroll
        for (int m = 0; m < 4; ++m)
#pragma unroll
            for (int n = 0; n < 4; ++n) {
                acc[m][n] = __builtin_amdgcn_mfma_f32_16x16x32_bf16(ah[m], bh[n], acc[m][n], 0, 0, 0);
                acc[m][n] = __builtin_amdgcn_mfma_f32_16x16x32_bf16(ah[m], bl[n], acc[m][n], 0, 0, 0);
                acc[m][n] = __builtin_amdgcn_mfma_f32_16x16x32_bf16(al[m], bh[n], acc[m][n], 0, 0, 0);
            }
        __syncthreads();   // drains vmcnt (next tile landed) + all waves done with cur
        cur ^= 1;
    }

    // epilogue: C/D layout col=lane&15, row=(lane>>4)*4+reg  [m89/m91]
    const int rh = lane >> 4;
    const long orow0 = brow + wm * 64;
    const int ocol0 = bcol + wn * 64;
#pragma unroll
    for (int m = 0; m < 4; ++m) {
#pragma unroll
        for (int r = 0; r < 4; ++r) {
            long row = orow0 + m * 16 + rh * 4 + r;
            long base = row * N + ocol0 + rl;
#pragma unroll
            for (int n = 0; n < 4; ++n) {
                float v = acc[m][n][r];
                long off = base + n * 16;
                if (ADD) v += __bfloat162float(Xah[off]) + __bfloat162float(Xal[off]);
                if (OUTF32) {
                    Of[off] = v;
                } else {
                    ushort h, l;
                    split2(v, h, l);
                    *reinterpret_cast<ushort*>(Oh + off) = h;
                    *reinterpret_cast<ushort*>(Ol + off) = l;
                }
            }
        }
    }
}

// ---------------- launcher ----------------

extern "C" void kernel_launch(void* const* d_in, const int* in_sizes, int n_in,
                              void* d_out, int out_size, void* d_ws, size_t ws_size,
                              hipStream_t stream) {
    (void)in_sizes; (void)n_in; (void)out_size; (void)ws_size;
    const float* A = (const float*)d_in[0];
    const float* B = (const float*)d_in[1];
    const float* C = (const float*)d_in[2];
    const float* u = (const float*)d_in[3];

    const size_t NN = (size_t)N * N;

    // X1 pair lives in d_out (2 * 16MB bf16 == 32MB f32 out buffer)
    bf16* X1h = (bf16*)d_out;
    bf16* X1l = X1h + (size_t)L * N;

    char* w = (char*)d_ws;
    bf16* X0h = (bf16*)w;                w += (size_t)L * N * 2;
    bf16* X0l = (bf16*)w;                w += (size_t)L * N * 2;
    bf16* Qh  = (bf16*)w;                w += 14 * NN * 2;   // per-round hi splits
    bf16* Ql  = (bf16*)w;                w += 14 * NN * 2;   // per-round lo splits
    float* M   = (float*)w;              w += NN * 4;
    float* MT  = (float*)w;              w += NN * 4;
    float* M2  = (float*)w;              w += NN * 4;
    float* BLm = (float*)w;              w += NN * 4;
    float* BT  = (float*)w;              w += NN * 4;
    float* Bbf = (float*)w;              w += NN * 4;
    float* Qa  = (float*)w;              w += NN * 4;
    float* QaT = (float*)w;              w += NN * 4;
    float* Qb  = (float*)w;              w += NN * 4;
    float* QbT = (float*)w;              w += NN * 4;
    bf16* Bbh  = (bf16*)w;               w += NN * 2;
    bf16* Bbl  = (bf16*)w;               w += NN * 2;
    bf16* Ch   = (bf16*)w;               w += NN * 2;
    bf16* Cl   = (bf16*)w;               w += NN * 2;
    bf16* scrh = (bf16*)w;               w += NN * 2;
    bf16* scrl = (bf16*)w;               w += NN * 2;
    bf16* zb   = (bf16*)w;               w += 1024;

    const float step = 1.0f / (float)L;

    dim3 b256(256);
    dim3 gEl((int)((NN + 255) / 256));
    dim3 bT(32, 8), gT(N / 32, N / 32);
    dim3 g64(N / 64, N / 64);
    dim3 gBig(L / 128, N / 128);
    dim3 gS4n((int)(NN / 4 / 256));
    dim3 gS4L((int)((size_t)L * N / 4 / 256));

    k_zeroinit<<<1, 256, 0, stream>>>((int*)zb);

    // ---- Q chain (all squarings up front, fused transpose+split epilogues) ----
    k_scale<<<gEl, b256, 0, stream>>>(A, M, step * 0.5f, (int)NN);
    k_transpose<<<gT, bT, 0, stream>>>(M, MT);
    k_qsq<false><<<g64, b256, 0, stream>>>(M, MT, M2, nullptr, scrh, scrl, 1.0f);  // M2 = M@M
    k_build<<<gEl, b256, 0, stream>>>(M, M2, Qa, BLm, Qh, Ql);  // Q_0 = Ab (+ split)
    k_transpose<<<gT, bT, 0, stream>>>(Qa, QaT);
    float* Qc = Qa; float* QcT = QaT; float* Qn = Qb; float* QnT = QbT;
    for (int r = 1; r < 14; ++r) {
        k_qsq<true><<<g64, b256, 0, stream>>>(Qc, QcT, Qn, QnT, Qh + r * NN, Ql + r * NN, 1.0f);
        float* t;
        t = Qc; Qc = Qn; Qn = t;
        t = QcT; QcT = QnT; QnT = t;
    }
    // Bb = step * BL @ B  (+ split)
    k_transpose<<<gT, bT, 0, stream>>>(B, BT);
    k_qsq<false><<<g64, b256, 0, stream>>>(BLm, BT, Bbf, nullptr, Bbh, Bbl, step);
    // input splits
    k_split4<<<gS4n, b256, 0, stream>>>(C, Ch, Cl, (int)(NN / 4));
    k_split4<<<gS4L, b256, 0, stream>>>(u, X1h, X1l, (int)((size_t)L * N / 4));

    // ---- big GEMMs, back-to-back ----
    // X0 = Bu = u @ Bb^T
    k_bigmm<false, false><<<gBig, b256, 0, stream>>>(
        X1h, X1l, Bbh, Bbl, nullptr, nullptr, X0h, X0l, nullptr, 0, zb);
    // doubling rounds: X[i] += Ab^(2^r) @ X[i - 2^r]
    for (int r = 0; r < 14; ++r) {
        bf16* Xih = (r & 1) ? X1h : X0h;  bf16* Xil = (r & 1) ? X1l : X0l;
        bf16* Xoh = (r & 1) ? X0h : X1h;  bf16* Xol = (r & 1) ? X0l : X1l;
        k_bigmm<true, false><<<gBig, b256, 0, stream>>>(
            Xih, Xil, Qh + r * NN, Ql + r * NN, Xih, Xil, Xoh, Xol, nullptr, 1 << r, zb);
    }
    // final: OUT = X0 @ C^T (f32, overwrites d_out)
    k_bigmm<false, true><<<gBig, b256, 0, stream>>>(
        X0h, X0l, Ch, Cl, nullptr, nullptr, nullptr, nullptr, (float*)d_out, 0, zb);
}

// Round 4
// 824.246 us; speedup vs baseline: 2.6250x; 1.0750x over previous
//
#include <hip/hip_runtime.h>
#include <hip/hip_bf16.h>

static constexpr int N = 512;    // state size == feature size
static constexpr int L = 16384;  // sequence length
static constexpr int BIGX = L / 128;   // 128 big blocks in x

typedef short s16x8 __attribute__((ext_vector_type(8)));
typedef float f32x4 __attribute__((ext_vector_type(4)));
using bf16 = __hip_bfloat16;

#define GPTR(p) ((const __attribute__((address_space(1))) void*)(p))
#define LPTR(p) ((__attribute__((address_space(3))) void*)(p))

__device__ __forceinline__ void gload16(const void* g, void* l) {
    __builtin_amdgcn_global_load_lds(GPTR(g), LPTR(l), 16, 0, 0);
}

__device__ __forceinline__ void split2(float v, ushort& h, ushort& l) {
    bf16 hb = __float2bfloat16(v);
    h = *reinterpret_cast<ushort*>(&hb);
    bf16 lb = __float2bfloat16(v - __bfloat162float(hb));
    l = *reinterpret_cast<ushort*>(&lb);
}
__device__ __forceinline__ float b2f(bf16 x) { return __bfloat162float(x); }

// ---------------- small setup kernels ----------------

__global__ void k_zeroinit(int* zb) { zb[threadIdx.x] = 0; }  // 1KB zeros

__global__ void k_scale(const float* __restrict__ A, float* __restrict__ M, float h, int n) {
    int i = blockIdx.x * 256 + threadIdx.x;
    if (i < n) M[i] = A[i] * h;
}

// D0 = 2(M+M^2) (f32 + split), BL = I + M + M^2
__global__ void k_buildD(const float* __restrict__ M, const float* __restrict__ M2,
                         float* __restrict__ D0f, bf16* __restrict__ Dh,
                         bf16* __restrict__ Dl, float* __restrict__ BLm) {
    int i = blockIdx.x * 256 + threadIdx.x;
    if (i >= N * N) return;
    float m = M[i], m2 = M2[i];
    float d = 2.0f * (m + m2);
    D0f[i] = d;
    ushort h, l;
    split2(d, h, l);
    *reinterpret_cast<ushort*>(Dh + i) = h;
    *reinterpret_cast<ushort*>(Dl + i) = l;
    BLm[i] = (((i >> 9) == (i & (N - 1))) ? 1.0f : 0.0f) + m + m2;
}

// vectorized f32 -> (hi, lo) bf16 split, 4 elems/thread
__global__ void k_split4(const float* __restrict__ in, bf16* __restrict__ hi,
                         bf16* __restrict__ lo, int n4) {
    int i = blockIdx.x * 256 + threadIdx.x;
    if (i >= n4) return;
    float4 v = reinterpret_cast<const float4*>(in)[i];
    ushort ht[4], lt[4];
    split2(v.x, ht[0], lt[0]);
    split2(v.y, ht[1], lt[1]);
    split2(v.z, ht[2], lt[2]);
    split2(v.w, ht[3], lt[3]);
    *reinterpret_cast<ushort4*>(hi + 4 * (size_t)i) = *reinterpret_cast<ushort4*>(ht);
    *reinterpret_cast<ushort4*>(lo + 4 * (size_t)i) = *reinterpret_cast<ushort4*>(lt);
}

// 512x512 f32 transpose
__global__ void k_transpose(const float* __restrict__ in, float* __restrict__ out) {
    __shared__ float t[32][33];
    int bx = blockIdx.x * 32, by = blockIdx.y * 32;
    int tx = threadIdx.x, ty = threadIdx.y;  // block 32x8
#pragma unroll
    for (int j = 0; j < 32; j += 8) t[ty + j][tx] = in[(by + ty + j) * N + bx + tx];
    __syncthreads();
#pragma unroll
    for (int j = 0; j < 32; j += 8) out[(bx + ty + j) * N + by + tx] = t[tx][ty + j];
}

// transpose + f32 master + bf16 split of the transpose
__global__ void k_tsplit(const float* __restrict__ in, float* __restrict__ of,
                         bf16* __restrict__ oh, bf16* __restrict__ ol) {
    __shared__ float t[32][33];
    int bx = blockIdx.x * 32, by = blockIdx.y * 32;
    int tx = threadIdx.x, ty = threadIdx.y;
#pragma unroll
    for (int j = 0; j < 32; j += 8) t[ty + j][tx] = in[(by + ty + j) * N + bx + tx];
    __syncthreads();
#pragma unroll
    for (int j = 0; j < 32; j += 8) {
        float v = t[tx][ty + j];
        size_t off = (size_t)(bx + ty + j) * N + by + tx;
        of[off] = v;
        ushort h, l;
        split2(v, h, l);
        *reinterpret_cast<ushort*>(oh + off) = h;
        *reinterpret_cast<ushort*>(ol + off) = l;
    }
}

// ---------------- f32 NT GEMM 64x64 + fused bf16-split epilogue (setup only) ----
__global__ __launch_bounds__(256) void k_qsq(
    const float* __restrict__ Asrc, const float* __restrict__ Bmat,
    float* __restrict__ OUT, bf16* __restrict__ Sh, bf16* __restrict__ Sl, float scale) {
    __shared__ float As[32][64];
    __shared__ float Bs[32][64];
    const int tid = threadIdx.x;
    const int brow = blockIdx.x * 64;
    const int bcol = blockIdx.y * 64;
    const int tx = tid & 15, ty = tid >> 4;
    float acc[4][4] = {};

    for (int k0 = 0; k0 < N; k0 += 32) {
#pragma unroll
        for (int q = 0; q < 2; ++q) {
            int idx = tid * 2 + q;
            int row = idx >> 3;
            int kq = (idx & 7) << 2;
            float4 va = *(const float4*)(Asrc + (long)(brow + row) * N + k0 + kq);
            As[kq + 0][row] = va.x; As[kq + 1][row] = va.y;
            As[kq + 2][row] = va.z; As[kq + 3][row] = va.w;
            float4 vb = *(const float4*)(Bmat + (long)(bcol + row) * N + k0 + kq);
            Bs[kq + 0][row] = vb.x; Bs[kq + 1][row] = vb.y;
            Bs[kq + 2][row] = vb.z; Bs[kq + 3][row] = vb.w;
        }
        __syncthreads();
#pragma unroll
        for (int kk = 0; kk < 32; ++kk) {
            float a[4], b[4];
            *(float4*)&a[0] = *(const float4*)&As[kk][ty * 4];
            *(float4*)&b[0] = *(const float4*)&Bs[kk][tx * 4];
#pragma unroll
            for (int i = 0; i < 4; ++i)
#pragma unroll
                for (int j = 0; j < 4; ++j) acc[i][j] = fmaf(a[i], b[j], acc[i][j]);
        }
        __syncthreads();
    }
#pragma unroll
    for (int i = 0; i < 4; ++i) {
        long off = (long)(brow + ty * 4 + i) * N + bcol + tx * 4;
        float4 o = make_float4(acc[i][0] * scale, acc[i][1] * scale,
                               acc[i][2] * scale, acc[i][3] * scale);
        *(float4*)(OUT + off) = o;
        ushort ht[4], lt[4];
        split2(o.x, ht[0], lt[0]); split2(o.y, ht[1], lt[1]);
        split2(o.z, ht[2], lt[2]); split2(o.w, ht[3], lt[3]);
        *reinterpret_cast<ushort4*>(Sh + off) = *reinterpret_cast<ushort4*>(ht);
        *reinterpret_cast<ushort4*>(Sl + off) = *reinterpret_cast<ushort4*>(lt);
    }
}

// ---------------- bf16x3 MFMA NT GEMM, 128x128 (Bu and final C GEMM) ----------
// OUT = A @ B^T, A/B as (hi,lo) pairs, 3-MFMA. OUTF32: f32 out, else split.
template <bool OUTF32>
__global__ __launch_bounds__(256, 2) void k_bigmm(
    const bf16* __restrict__ Ah, const bf16* __restrict__ Al,
    const bf16* __restrict__ Bh, const bf16* __restrict__ Bl,
    bf16* __restrict__ Oh, bf16* __restrict__ Ol, float* __restrict__ Of)
{
    __shared__ char smem[65536];
    const int tid = threadIdx.x;
    const int wave = tid >> 6, lane = tid & 63;
    const long brow = (long)blockIdx.x * 128;
    const int bcol = blockIdx.y * 128;
    const int wm = wave >> 1, wn = wave & 1;

    f32x4 acc[4][4];
#pragma unroll
    for (int m = 0; m < 4; ++m)
#pragma unroll
        for (int n = 0; n < 4; ++n) acc[m][n] = (f32x4){0.f, 0.f, 0.f, 0.f};

    const char* pAh[2]; const char* pAl[2]; const char* pBh[2]; const char* pBl[2];
    int wb[2];
#pragma unroll
    for (int q = 0; q < 2; ++q) {
        int idx = q * 256 + tid;
        int row = idx >> 2, slot = idx & 3;
        int sp = slot ^ ((row >> 1) & 3);
        pAh[q] = (const char*)(Ah + (brow + row) * N + sp * 8);
        pAl[q] = (const char*)(Al + (brow + row) * N + sp * 8);
        long eb = (long)(bcol + row) * N + sp * 8;
        pBh[q] = (const char*)(Bh + eb);
        pBl[q] = (const char*)(Bl + eb);
        wb[q] = (q * 256 + wave * 64) * 16;
    }
    const int slot = lane >> 4;
    const int rl = lane & 15;

#pragma unroll
    for (int q = 0; q < 2; ++q) {
        gload16(pAh[q], smem + 0     + wb[q]);
        gload16(pAl[q], smem + 8192  + wb[q]);
        gload16(pBh[q], smem + 16384 + wb[q]);
        gload16(pBl[q], smem + 24576 + wb[q]);
    }
    __syncthreads();

    int cur = 0;
    for (int t = 0; t < 16; ++t) {
        const char* base = smem + cur * 32768;
        s16x8 ah[4], al[4], bh[4], bl[4];
#pragma unroll
        for (int m = 0; m < 4; ++m) {
            int row = wm * 64 + m * 16 + rl;
            int off = row * 64 + (slot ^ ((row >> 1) & 3)) * 16;
            ah[m] = *reinterpret_cast<const s16x8*>(base + off);
            al[m] = *reinterpret_cast<const s16x8*>(base + 8192 + off);
        }
#pragma unroll
        for (int n = 0; n < 4; ++n) {
            int row = wn * 64 + n * 16 + rl;
            int off = row * 64 + (slot ^ ((row >> 1) & 3)) * 16;
            bh[n] = *reinterpret_cast<const s16x8*>(base + 16384 + off);
            bl[n] = *reinterpret_cast<const s16x8*>(base + 24576 + off);
        }
        if (t + 1 < 16) {
            const int kb = (t + 1) * 64;
            char* nb = smem + (cur ^ 1) * 32768;
#pragma unroll
            for (int q = 0; q < 2; ++q) {
                gload16(pAh[q] + kb, nb + 0     + wb[q]);
                gload16(pAl[q] + kb, nb + 8192  + wb[q]);
                gload16(pBh[q] + kb, nb + 16384 + wb[q]);
                gload16(pBl[q] + kb, nb + 24576 + wb[q]);
            }
        }
#pragma unroll
        for (int m = 0; m < 4; ++m)
#pragma unroll
            for (int n = 0; n < 4; ++n) {
                acc[m][n] = __builtin_amdgcn_mfma_f32_16x16x32_bf16(ah[m], bh[n], acc[m][n], 0, 0, 0);
                acc[m][n] = __builtin_amdgcn_mfma_f32_16x16x32_bf16(ah[m], bl[n], acc[m][n], 0, 0, 0);
                acc[m][n] = __builtin_amdgcn_mfma_f32_16x16x32_bf16(al[m], bh[n], acc[m][n], 0, 0, 0);
            }
        __syncthreads();
        cur ^= 1;
    }

    const int rh = lane >> 4;
    const long orow0 = brow + wm * 64;
    const int ocol0 = bcol + wn * 64;
#pragma unroll
    for (int m = 0; m < 4; ++m) {
#pragma unroll
        for (int r = 0; r < 4; ++r) {
            long row = orow0 + m * 16 + rh * 4 + r;
            long base = row * N + ocol0 + rl;
#pragma unroll
            for (int n = 0; n < 4; ++n) {
                float v = acc[m][n][r];
                long off = base + n * 16;
                if (OUTF32) {
                    Of[off] = v;
                } else {
                    ushort h, l;
                    split2(v, h, l);
                    *reinterpret_cast<ushort*>(Oh + off) = h;
                    *reinterpret_cast<ushort*>(Ol + off) = l;
                }
            }
        }
    }
}

// ---------------- D-form doubling round + fused D-squaring ----------------
// Big blocks (bx < BIGX): Xo[i] = Xi[i] + Xi[i-s] + (Xs @ D^T)[i]
//   NM=1: 1 MFMA (Xs_hi @ D_hi), BK=64.  NM=3: bf16x3, BK=32.
// Square blocks (bx >= BIGX, 64 of them): Dnext = D^2 + 2D via (A=D^T,B=D) NT
//   producing (D^2)^T tiles; epilogue writes next-D both orientations + f32 D^T.
template <int NM>
__global__ __launch_bounds__(256, 2) void k_round(
    const bf16* __restrict__ Xih, const bf16* __restrict__ Xil,
    bf16* __restrict__ Xoh, bf16* __restrict__ Xol,
    const bf16* __restrict__ Dh, const bf16* __restrict__ Dl,
    const bf16* __restrict__ DTh, const bf16* __restrict__ DTl,
    const float* __restrict__ DTf,
    bf16* __restrict__ Dnh, bf16* __restrict__ Dnl,
    bf16* __restrict__ DTnh, bf16* __restrict__ DTnl, float* __restrict__ DTfn,
    int shift, int doSq, const bf16* __restrict__ zb)
{
    __shared__ char smem[65536];
    const int tid = threadIdx.x;
    const int wave = tid >> 6, lane = tid & 63;
    const int wm = wave >> 1, wn = wave & 1;
    const int rl = lane & 15, rh = lane >> 4;

    if (blockIdx.x >= BIGX) {
        // ======== D-squaring path ========
        if (!doSq) return;
        int sidx = (blockIdx.x - BIGX) * (int)gridDim.y + blockIdx.y;  // 0..63
        const int ti = (sidx >> 3) * 64, tj = (sidx & 7) * 64;

        f32x4 acc[2][2];
#pragma unroll
        for (int m = 0; m < 2; ++m)
#pragma unroll
            for (int n = 0; n < 2; ++n) acc[m][n] = (f32x4){0.f, 0.f, 0.f, 0.f};

        int row = tid >> 2, slot = tid & 3;
        int sp = slot ^ ((row >> 1) & 3);
        const char* pAh = (const char*)(DTh + (size_t)(ti + row) * N + sp * 8);
        const char* pAl = (const char*)(DTl + (size_t)(ti + row) * N + sp * 8);
        const char* pBh = (const char*)(Dh + (size_t)(tj + row) * N + sp * 8);
        const char* pBl = (const char*)(Dl + (size_t)(tj + row) * N + sp * 8);
        const int wb = wave * 1024;

        gload16(pAh, smem + 0     + wb);
        gload16(pAl, smem + 4096  + wb);
        gload16(pBh, smem + 8192  + wb);
        gload16(pBl, smem + 12288 + wb);
        __syncthreads();

        int cur = 0;
        for (int t = 0; t < 16; ++t) {
            const char* base = smem + cur * 16384;
            s16x8 ah[2], al[2], bh[2], bl[2];
#pragma unroll
            for (int m = 0; m < 2; ++m) {
                int r2 = wm * 32 + m * 16 + rl;
                int off = r2 * 64 + (rh ^ ((r2 >> 1) & 3)) * 16;
                ah[m] = *reinterpret_cast<const s16x8*>(base + off);
                al[m] = *reinterpret_cast<const s16x8*>(base + 4096 + off);
            }
#pragma unroll
            for (int n = 0; n < 2; ++n) {
                int r2 = wn * 32 + n * 16 + rl;
                int off = r2 * 64 + (rh ^ ((r2 >> 1) & 3)) * 16;
                bh[n] = *reinterpret_cast<const s16x8*>(base + 8192 + off);
                bl[n] = *reinterpret_cast<const s16x8*>(base + 12288 + off);
            }
            if (t + 1 < 16) {
                const int kb = (t + 1) * 64;
                char* nb = smem + (cur ^ 1) * 16384;
                gload16(pAh + kb, nb + 0     + wb);
                gload16(pAl + kb, nb + 4096  + wb);
                gload16(pBh + kb, nb + 8192  + wb);
                gload16(pBl + kb, nb + 12288 + wb);
            }
#pragma unroll
            for (int m = 0; m < 2; ++m)
#pragma unroll
                for (int n = 0; n < 2; ++n) {
                    acc[m][n] = __builtin_amdgcn_mfma_f32_16x16x32_bf16(ah[m], bh[n], acc[m][n], 0, 0, 0);
                    acc[m][n] = __builtin_amdgcn_mfma_f32_16x16x32_bf16(ah[m], bl[n], acc[m][n], 0, 0, 0);
                    acc[m][n] = __builtin_amdgcn_mfma_f32_16x16x32_bf16(al[m], bh[n], acc[m][n], 0, 0, 0);
                }
            __syncthreads();
            cur ^= 1;
        }

#pragma unroll
        for (int m = 0; m < 2; ++m)
#pragma unroll
            for (int n = 0; n < 2; ++n)
#pragma unroll
                for (int q = 0; q < 4; ++q) {
                    int i = ti + wm * 32 + m * 16 + rh * 4 + q;
                    int j = tj + wn * 32 + n * 16 + rl;
                    size_t off = (size_t)i * N + j;
                    float v = acc[m][n][q] + 2.0f * DTf[off];   // (D^2)^T + 2 D^T
                    DTfn[off] = v;
                    ushort h, l;
                    split2(v, h, l);
                    *reinterpret_cast<ushort*>(DTnh + off) = h;
                    *reinterpret_cast<ushort*>(DTnl + off) = l;
                    size_t offT = (size_t)j * N + i;
                    *reinterpret_cast<ushort*>(Dnh + offT) = h;
                    *reinterpret_cast<ushort*>(Dnl + offT) = l;
                }
        return;
    }

    // ======== big doubling path ========
    const long brow = (long)blockIdx.x * 128;
    const int bcol = blockIdx.y * 128;

    if (brow + 127 < (long)shift) {
        // fully below shift: Xo = Xi (copy)
#pragma unroll
        for (int j = 0; j < 8; ++j) {
            int c = j * 256 + tid;
            long off = (brow + (c >> 4)) * N + bcol + (c & 15) * 8;
            *reinterpret_cast<int4*>(Xoh + off) = *reinterpret_cast<const int4*>(Xih + off);
            *reinterpret_cast<int4*>(Xol + off) = *reinterpret_cast<const int4*>(Xil + off);
        }
        return;
    }

    f32x4 acc[4][4];
#pragma unroll
    for (int m = 0; m < 4; ++m)
#pragma unroll
        for (int n = 0; n < 4; ++n) acc[m][n] = (f32x4){0.f, 0.f, 0.f, 0.f};

    if constexpr (NM == 1) {
        // BK=64; LDS: A(Xs_hi) [0,16K) B(D_hi) [16K,32K); dbuf stride 32K
        const char* pA[4]; const char* pB[4]; int wb[4];
#pragma unroll
        for (int q = 0; q < 4; ++q) {
            int idx = q * 256 + tid;
            int row = idx >> 3, slot = idx & 7;
            int sp = slot ^ (row & 7);
            long gra = brow + row - shift;
            pA[q] = (gra >= 0) ? (const char*)(Xih + gra * N + sp * 8)
                               : (const char*)(zb + sp * 8);
            pB[q] = (const char*)(Dh + (size_t)(bcol + row) * N + sp * 8);
            wb[q] = (q * 256 + wave * 64) * 16;
        }
#pragma unroll
        for (int q = 0; q < 4; ++q) {
            gload16(pA[q], smem + wb[q]);
            gload16(pB[q], smem + 16384 + wb[q]);
        }
        __syncthreads();

        int cur = 0;
        for (int t = 0; t < 8; ++t) {
            const char* base = smem + cur * 32768;
            s16x8 a[4][2], b[4][2];
#pragma unroll
            for (int m = 0; m < 4; ++m) {
                int row = wm * 64 + m * 16 + rl;
                int ro = row * 128, rs = row & 7;
#pragma unroll
                for (int kk = 0; kk < 2; ++kk) {
                    int s = (kk * 4 + rh) ^ rs;
                    a[m][kk] = *reinterpret_cast<const s16x8*>(base + ro + s * 16);
                }
            }
#pragma unroll
            for (int n = 0; n < 4; ++n) {
                int row = wn * 64 + n * 16 + rl;
                int ro = row * 128, rs = row & 7;
#pragma unroll
                for (int kk = 0; kk < 2; ++kk) {
                    int s = (kk * 4 + rh) ^ rs;
                    b[n][kk] = *reinterpret_cast<const s16x8*>(base + 16384 + ro + s * 16);
                }
            }
            if (t + 1 < 8) {
                const int kb = (t + 1) * 128;
                char* nb = smem + (cur ^ 1) * 32768;
#pragma unroll
                for (int q = 0; q < 4; ++q) {
                    gload16(pA[q] + kb, nb + wb[q]);
                    gload16(pB[q] + kb, nb + 16384 + wb[q]);
                }
            }
#pragma unroll
            for (int kk = 0; kk < 2; ++kk)
#pragma unroll
                for (int m = 0; m < 4; ++m)
#pragma unroll
                    for (int n = 0; n < 4; ++n)
                        acc[m][n] = __builtin_amdgcn_mfma_f32_16x16x32_bf16(
                            a[m][kk], b[n][kk], acc[m][n], 0, 0, 0);
            __syncthreads();
            cur ^= 1;
        }
    } else {
        // BK=32 bf16x3; LDS: Xs_h/Xs_l/D_h/D_l at 0/8K/16K/24K; dbuf stride 32K
        const char* pAh[2]; const char* pAl[2]; const char* pBh[2]; const char* pBl[2];
        int wb[2];
#pragma unroll
        for (int q = 0; q < 2; ++q) {
            int idx = q * 256 + tid;
            int row = idx >> 2, slot = idx & 3;
            int sp = slot ^ ((row >> 1) & 3);
            long gra = brow + row - shift;
            pAh[q] = (gra >= 0) ? (const char*)(Xih + gra * N + sp * 8)
                                : (const char*)(zb + sp * 8);
            pAl[q] = (gra >= 0) ? (const char*)(Xil + gra * N + sp * 8)
                                : (const char*)(zb + sp * 8);
            long eb = (long)(bcol + row) * N + sp * 8;
            pBh[q] = (const char*)(Dh + eb);
            pBl[q] = (const char*)(Dl + eb);
            wb[q] = (q * 256 + wave * 64) * 16;
        }
#pragma unroll
        for (int q = 0; q < 2; ++q) {
            gload16(pAh[q], smem + 0     + wb[q]);
            gload16(pAl[q], smem + 8192  + wb[q]);
            gload16(pBh[q], smem + 16384 + wb[q]);
            gload16(pBl[q], smem + 24576 + wb[q]);
        }
        __syncthreads();

        int cur = 0;
        for (int t = 0; t < 16; ++t) {
            const char* base = smem + cur * 32768;
            s16x8 ah[4], al[4], bh[4], bl[4];
#pragma unroll
            for (int m = 0; m < 4; ++m) {
                int row = wm * 64 + m * 16 + rl;
                int off = row * 64 + ((rh) ^ ((row >> 1) & 3)) * 16;
                ah[m] = *reinterpret_cast<const s16x8*>(base + off);
                al[m] = *reinterpret_cast<const s16x8*>(base + 8192 + off);
            }
#pragma unroll
            for (int n = 0; n < 4; ++n) {
                int row = wn * 64 + n * 16 + rl;
                int off = row * 64 + ((rh) ^ ((row >> 1) & 3)) * 16;
                bh[n] = *reinterpret_cast<const s16x8*>(base + 16384 + off);
                bl[n] = *reinterpret_cast<const s16x8*>(base + 24576 + off);
            }
            if (t + 1 < 16) {
                const int kb = (t + 1) * 64;
                char* nb = smem + (cur ^ 1) * 32768;
#pragma unroll
                for (int q = 0; q < 2; ++q) {
                    gload16(pAh[q] + kb, nb + 0     + wb[q]);
                    gload16(pAl[q] + kb, nb + 8192  + wb[q]);
                    gload16(pBh[q] + kb, nb + 16384 + wb[q]);
                    gload16(pBl[q] + kb, nb + 24576 + wb[q]);
                }
            }
#pragma unroll
            for (int m = 0; m < 4; ++m)
#pragma unroll
                for (int n = 0; n < 4; ++n) {
                    acc[m][n] = __builtin_amdgcn_mfma_f32_16x16x32_bf16(ah[m], bh[n], acc[m][n], 0, 0, 0);
                    acc[m][n] = __builtin_amdgcn_mfma_f32_16x16x32_bf16(ah[m], bl[n], acc[m][n], 0, 0, 0);
                    acc[m][n] = __builtin_amdgcn_mfma_f32_16x16x32_bf16(al[m], bh[n], acc[m][n], 0, 0, 0);
                }
            __syncthreads();
            cur ^= 1;
        }
    }

    // epilogue: v = acc + X[i] + X[i-s]; split-write
    const long orow0 = brow + wm * 64;
    const int ocol0 = bcol + wn * 64;
#pragma unroll
    for (int m = 0; m < 4; ++m) {
#pragma unroll
        for (int q = 0; q < 4; ++q) {
            long gi = orow0 + m * 16 + rh * 4 + q;
            long gs = gi - shift;
            long base = gi * N + ocol0 + rl;
            long bases = gs * N + ocol0 + rl;
            bool hasS = gs >= 0;
#pragma unroll
            for (int n = 0; n < 4; ++n) {
                long off = base + n * 16;
                float v = acc[m][n][q] + b2f(Xih[off]) + b2f(Xil[off]);
                if (hasS) {
                    long o2 = bases + n * 16;
                    v += b2f(Xih[o2]) + b2f(Xil[o2]);
                }
                ushort h, l;
                split2(v, h, l);
                *reinterpret_cast<ushort*>(Xoh + off) = h;
                *reinterpret_cast<ushort*>(Xol + off) = l;
            }
        }
    }
}

// ---------------- launcher ----------------

extern "C" void kernel_launch(void* const* d_in, const int* in_sizes, int n_in,
                              void* d_out, int out_size, void* d_ws, size_t ws_size,
                              hipStream_t stream) {
    (void)in_sizes; (void)n_in; (void)out_size; (void)ws_size;
    const float* A = (const float*)d_in[0];
    const float* B = (const float*)d_in[1];
    const float* C = (const float*)d_in[2];
    const float* u = (const float*)d_in[3];

    const size_t NN = (size_t)N * N;
    const size_t LN = (size_t)L * N;

    // X1 pair lives in d_out (2 * 16MB bf16 == 32MB f32 out buffer)
    bf16* X1h = (bf16*)d_out;
    bf16* X1l = X1h + LN;

    char* w = (char*)d_ws;
    bf16* X0h = (bf16*)w;      w += LN * 2;
    bf16* X0l = (bf16*)w;      w += LN * 2;
    bf16 *Dh_[2], *Dl_[2], *DTh_[2], *DTl_[2];
    float* DTf_[2];
    for (int s = 0; s < 2; ++s) {
        Dh_[s]  = (bf16*)w;    w += NN * 2;
        Dl_[s]  = (bf16*)w;    w += NN * 2;
        DTh_[s] = (bf16*)w;    w += NN * 2;
        DTl_[s] = (bf16*)w;    w += NN * 2;
        DTf_[s] = (float*)w;   w += NN * 4;
    }
    float* M   = (float*)w;    w += NN * 4;
    float* MT  = (float*)w;    w += NN * 4;
    float* M2  = (float*)w;    w += NN * 4;
    float* BLm = (float*)w;    w += NN * 4;
    float* BT  = (float*)w;    w += NN * 4;
    float* Bbf = (float*)w;    w += NN * 4;
    float* D0f = (float*)w;    w += NN * 4;
    bf16* Bbh  = (bf16*)w;     w += NN * 2;
    bf16* Bbl  = (bf16*)w;     w += NN * 2;
    bf16* Ch   = (bf16*)w;     w += NN * 2;
    bf16* Cl   = (bf16*)w;     w += NN * 2;
    bf16* scrh = (bf16*)w;     w += NN * 2;
    bf16* scrl = (bf16*)w;     w += NN * 2;
    bf16* zb   = (bf16*)w;     w += 1024;

    const float step = 1.0f / (float)L;

    dim3 b256(256);
    dim3 gEl((int)((NN + 255) / 256));
    dim3 bT(32, 8), gT(N / 32, N / 32);
    dim3 g64(N / 64, N / 64);
    dim3 gBig(BIGX, N / 128);
    dim3 gRound(BIGX + 16, N / 128);   // +64 square blocks
    dim3 gS4n((int)(NN / 4 / 256));
    dim3 gS4L((int)(LN / 4 / 256));

    k_zeroinit<<<1, 256, 0, stream>>>((int*)zb);

    // ---- setup: M, M^2, D_0 (both orientations + splits), Bb, input splits ----
    k_scale<<<gEl, b256, 0, stream>>>(A, M, step * 0.5f, (int)NN);
    k_transpose<<<gT, bT, 0, stream>>>(M, MT);
    k_qsq<<<g64, b256, 0, stream>>>(M, MT, M2, scrh, scrl, 1.0f);           // M2 = M@M
    k_buildD<<<gEl, b256, 0, stream>>>(M, M2, D0f, Dh_[0], Dl_[0], BLm);    // D_0, BL
    k_tsplit<<<gT, bT, 0, stream>>>(D0f, DTf_[0], DTh_[0], DTl_[0]);        // D_0^T
    k_transpose<<<gT, bT, 0, stream>>>(B, BT);
    k_qsq<<<g64, b256, 0, stream>>>(BLm, BT, Bbf, Bbh, Bbl, step);          // Bb
    k_split4<<<gS4n, b256, 0, stream>>>(C, Ch, Cl, (int)(NN / 4));
    k_split4<<<gS4L, b256, 0, stream>>>(u, X1h, X1l, (int)(LN / 4));

    // ---- Bu = u @ Bb^T ----
    k_bigmm<false><<<gBig, b256, 0, stream>>>(X1h, X1l, Bbh, Bbl, X0h, X0l, nullptr);

    // ---- 14 doubling rounds (square of D_{r+1} fused into round r) ----
    for (int r = 0; r < 14; ++r) {
        int s = r & 1, nx = s ^ 1;
        bf16* Xih = (r & 1) ? X1h : X0h;  bf16* Xil = (r & 1) ? X1l : X0l;
        bf16* Xoh = (r & 1) ? X0h : X1h;  bf16* Xol = (r & 1) ? X0l : X1l;
        int doSq = (r < 13) ? 1 : 0;
        if (r < 10)
            k_round<1><<<gRound, b256, 0, stream>>>(
                Xih, Xil, Xoh, Xol,
                Dh_[s], Dl_[s], DTh_[s], DTl_[s], DTf_[s],
                Dh_[nx], Dl_[nx], DTh_[nx], DTl_[nx], DTf_[nx],
                1 << r, doSq, zb);
        else
            k_round<3><<<gRound, b256, 0, stream>>>(
                Xih, Xil, Xoh, Xol,
                Dh_[s], Dl_[s], DTh_[s], DTl_[s], DTf_[s],
                Dh_[nx], Dl_[nx], DTh_[nx], DTl_[nx], DTf_[nx],
                1 << r, doSq, zb);
    }

    // ---- final: OUT = X0 @ C^T (f32) ----
    k_bigmm<true><<<gBig, b256, 0, stream>>>(X0h, X0l, Ch, Cl, nullptr, nullptr, (float*)d_out);
}

// Round 5
// 812.055 us; speedup vs baseline: 2.6644x; 1.0150x over previous
//
#include <hip/hip_runtime.h>
#include <hip/hip_bf16.h>

static constexpr int N = 512;    // state size == feature size
static constexpr int L = 16384;  // sequence length

typedef short s16x8 __attribute__((ext_vector_type(8)));
typedef float f32x4 __attribute__((ext_vector_type(4)));
using bf16 = __hip_bfloat16;

#define GPTR(p) ((const __attribute__((address_space(1))) void*)(p))
#define LPTR(p) ((__attribute__((address_space(3))) void*)(p))
__device__ __forceinline__ void gload16(const void* g, void* l) {
    __builtin_amdgcn_global_load_lds(GPTR(g), LPTR(l), 16, 0, 0);
}

__device__ __forceinline__ void split2(float v, ushort& h, ushort& l) {
    bf16 hb = __float2bfloat16(v);
    h = *reinterpret_cast<ushort*>(&hb);
    bf16 lb = __float2bfloat16(v - __bfloat162float(hb));
    l = *reinterpret_cast<ushort*>(&lb);
}

// ---------------- small setup kernels ----------------

__global__ void k_scale(const float* __restrict__ A, float* __restrict__ M, float h, int n) {
    int i = blockIdx.x * 256 + threadIdx.x;
    if (i < n) M[i] = A[i] * h;
}

// D0 = 2(M+M^2) (f32 + split), BL = I + M + M^2
__global__ void k_buildD(const float* __restrict__ M, const float* __restrict__ M2,
                         float* __restrict__ D0f, bf16* __restrict__ Dh,
                         bf16* __restrict__ Dl, float* __restrict__ BLm) {
    int i = blockIdx.x * 256 + threadIdx.x;
    if (i >= N * N) return;
    float m = M[i], m2 = M2[i];
    float d = 2.0f * (m + m2);
    D0f[i] = d;
    ushort h, l;
    split2(d, h, l);
    *reinterpret_cast<ushort*>(Dh + i) = h;
    *reinterpret_cast<ushort*>(Dl + i) = l;
    BLm[i] = (((i >> 9) == (i & (N - 1))) ? 1.0f : 0.0f) + m + m2;
}

// vectorized f32 -> (hi, lo) bf16 split, 4 elems/thread
__global__ void k_split4(const float* __restrict__ in, bf16* __restrict__ hi,
                         bf16* __restrict__ lo, int n4) {
    int i = blockIdx.x * 256 + threadIdx.x;
    if (i >= n4) return;
    float4 v = reinterpret_cast<const float4*>(in)[i];
    ushort ht[4], lt[4];
    split2(v.x, ht[0], lt[0]);
    split2(v.y, ht[1], lt[1]);
    split2(v.z, ht[2], lt[2]);
    split2(v.w, ht[3], lt[3]);
    *reinterpret_cast<ushort4*>(hi + 4 * (size_t)i) = *reinterpret_cast<ushort4*>(ht);
    *reinterpret_cast<ushort4*>(lo + 4 * (size_t)i) = *reinterpret_cast<ushort4*>(lt);
}

// 512x512 f32 transpose
__global__ void k_transpose(const float* __restrict__ in, float* __restrict__ out) {
    __shared__ float t[32][33];
    int bx = blockIdx.x * 32, by = blockIdx.y * 32;
    int tx = threadIdx.x, ty = threadIdx.y;  // block 32x8
#pragma unroll
    for (int j = 0; j < 32; j += 8) t[ty + j][tx] = in[(by + ty + j) * N + bx + tx];
    __syncthreads();
#pragma unroll
    for (int j = 0; j < 32; j += 8) out[(bx + ty + j) * N + by + tx] = t[tx][ty + j];
}

// transpose + f32 master + bf16 split of the transpose
__global__ void k_tsplit(const float* __restrict__ in, float* __restrict__ of,
                         bf16* __restrict__ oh, bf16* __restrict__ ol) {
    __shared__ float t[32][33];
    int bx = blockIdx.x * 32, by = blockIdx.y * 32;
    int tx = threadIdx.x, ty = threadIdx.y;
#pragma unroll
    for (int j = 0; j < 32; j += 8) t[ty + j][tx] = in[(by + ty + j) * N + bx + tx];
    __syncthreads();
#pragma unroll
    for (int j = 0; j < 32; j += 8) {
        float v = t[tx][ty + j];
        size_t off = (size_t)(bx + ty + j) * N + by + tx;
        of[off] = v;
        ushort h, l;
        split2(v, h, l);
        *reinterpret_cast<ushort*>(oh + off) = h;
        *reinterpret_cast<ushort*>(ol + off) = l;
    }
}

// ---------------- f32 NT GEMM 64x64 + fused bf16-split epilogue (setup only) ----
__global__ __launch_bounds__(256) void k_qsq(
    const float* __restrict__ Asrc, const float* __restrict__ Bmat,
    float* __restrict__ OUT, bf16* __restrict__ Sh, bf16* __restrict__ Sl, float scale) {
    __shared__ float As[32][64];
    __shared__ float Bs[32][64];
    const int tid = threadIdx.x;
    const int brow = blockIdx.x * 64;
    const int bcol = blockIdx.y * 64;
    const int tx = tid & 15, ty = tid >> 4;
    float acc[4][4] = {};

    for (int k0 = 0; k0 < N; k0 += 32) {
#pragma unroll
        for (int q = 0; q < 2; ++q) {
            int idx = tid * 2 + q;
            int row = idx >> 3;
            int kq = (idx & 7) << 2;
            float4 va = *(const float4*)(Asrc + (long)(brow + row) * N + k0 + kq);
            As[kq + 0][row] = va.x; As[kq + 1][row] = va.y;
            As[kq + 2][row] = va.z; As[kq + 3][row] = va.w;
            float4 vb = *(const float4*)(Bmat + (long)(bcol + row) * N + k0 + kq);
            Bs[kq + 0][row] = vb.x; Bs[kq + 1][row] = vb.y;
            Bs[kq + 2][row] = vb.z; Bs[kq + 3][row] = vb.w;
        }
        __syncthreads();
#pragma unroll
        for (int kk = 0; kk < 32; ++kk) {
            float a[4], b[4];
            *(float4*)&a[0] = *(const float4*)&As[kk][ty * 4];
            *(float4*)&b[0] = *(const float4*)&Bs[kk][tx * 4];
#pragma unroll
            for (int i = 0; i < 4; ++i)
#pragma unroll
                for (int j = 0; j < 4; ++j) acc[i][j] = fmaf(a[i], b[j], acc[i][j]);
        }
        __syncthreads();
    }
#pragma unroll
    for (int i = 0; i < 4; ++i) {
        long off = (long)(brow + ty * 4 + i) * N + bcol + tx * 4;
        float4 o = make_float4(acc[i][0] * scale, acc[i][1] * scale,
                               acc[i][2] * scale, acc[i][3] * scale);
        *(float4*)(OUT + off) = o;
        ushort ht[4], lt[4];
        split2(o.x, ht[0], lt[0]); split2(o.y, ht[1], lt[1]);
        split2(o.z, ht[2], lt[2]); split2(o.w, ht[3], lt[3]);
        *reinterpret_cast<ushort4*>(Sh + off) = *reinterpret_cast<ushort4*>(ht);
        *reinterpret_cast<ushort4*>(Sl + off) = *reinterpret_cast<ushort4*>(lt);
    }
}

// ---------------- main MFMA kernel: doubling round / plain GEMM ----------------
// MODE 0 (round): big blocks: Xo[i] = Xi[i] + Xi[i-s] + (Xi[i-s] @ D^T)  (f32 X)
//                 sq blocks (bx >= L/128): Dnext = D^2 + 2D (both orientations)
// MODE 1 (plain): Xo = Xi @ Bp^T  (f32 out; used for Bu and the final C GEMM)
// NM=1: 1 MFMA (Ahi@Bhi);  NM=3: bf16x3.
// A is f32 in global, reg-staged with in-flight hi/lo split; B is a bf16 pair
// staged via global_load_lds with pre-swizzled source.
template <int NM, int MODE>
__global__ __launch_bounds__(256, (NM == 1 ? 3 : 2)) void k_round(
    const float* __restrict__ Xi, float* __restrict__ Xo,
    const bf16* __restrict__ Bph, const bf16* __restrict__ Bpl,
    const bf16* __restrict__ DTh, const bf16* __restrict__ DTl,
    const float* __restrict__ DTf,
    bf16* __restrict__ Dnh, bf16* __restrict__ Dnl,
    bf16* __restrict__ DTnh, bf16* __restrict__ DTnl, float* __restrict__ DTfn,
    int shift, int doSq)
{
    constexpr int LB = (NM == 1 ? 16384 : 32768);   // bytes per LDS buffer
    constexpr int BH = (NM == 1 ? 8192 : 16384);    // B-hi region offset
    __shared__ char smem[2 * LB];
    const int tid = threadIdx.x;
    const int wave = tid >> 6, lane = tid & 63;
    const int wm = wave >> 1, wn = wave & 1;
    const int rl = lane & 15, rh = lane >> 4;

    if (MODE == 0 && blockIdx.x >= (L / 128)) {
        // ======== D-squaring path (64 blocks) ========
        if (!doSq) return;
        int sidx = (blockIdx.x - (L / 128)) * (int)gridDim.y + blockIdx.y;  // 0..63
        const int ti = (sidx >> 3) * 64, tj = (sidx & 7) * 64;

        f32x4 acc[2][2];
#pragma unroll
        for (int m = 0; m < 2; ++m)
#pragma unroll
            for (int n = 0; n < 2; ++n) acc[m][n] = (f32x4){0.f, 0.f, 0.f, 0.f};

        int row = tid >> 2, slot = tid & 3;
        int sp = slot ^ ((row >> 1) & 3);
        const char* pAh = (const char*)(DTh + (size_t)(ti + row) * N + sp * 8);
        const char* pAl = (const char*)(DTl + (size_t)(ti + row) * N + sp * 8);
        const char* pBh = (const char*)(Bph + (size_t)(tj + row) * N + sp * 8);
        const char* pBl = (const char*)(Bpl + (size_t)(tj + row) * N + sp * 8);
        const int wb = wave * 1024;

        gload16(pAh, smem + 0     + wb);
        gload16(pAl, smem + 4096  + wb);
        gload16(pBh, smem + 8192  + wb);
        gload16(pBl, smem + 12288 + wb);
        __syncthreads();

#pragma unroll
        for (int t = 0; t < 16; ++t) {
            const char* base = smem + (t & 1) * 16384;
            s16x8 ah[2], al[2], bh[2], bl[2];
#pragma unroll
            for (int m = 0; m < 2; ++m) {
                int r2 = wm * 32 + m * 16 + rl;
                int off = r2 * 64 + (rh ^ ((r2 >> 1) & 3)) * 16;
                ah[m] = *reinterpret_cast<const s16x8*>(base + off);
                al[m] = *reinterpret_cast<const s16x8*>(base + 4096 + off);
            }
#pragma unroll
            for (int n = 0; n < 2; ++n) {
                int r2 = wn * 32 + n * 16 + rl;
                int off = r2 * 64 + (rh ^ ((r2 >> 1) & 3)) * 16;
                bh[n] = *reinterpret_cast<const s16x8*>(base + 8192 + off);
                bl[n] = *reinterpret_cast<const s16x8*>(base + 12288 + off);
            }
            if (t + 1 < 16) {
                const int kb = (t + 1) * 64;
                char* nb = smem + ((t + 1) & 1) * 16384;
                gload16(pAh + kb, nb + 0     + wb);
                gload16(pAl + kb, nb + 4096  + wb);
                gload16(pBh + kb, nb + 8192  + wb);
                gload16(pBl + kb, nb + 12288 + wb);
            }
#pragma unroll
            for (int m = 0; m < 2; ++m)
#pragma unroll
                for (int n = 0; n < 2; ++n) {
                    acc[m][n] = __builtin_amdgcn_mfma_f32_16x16x32_bf16(ah[m], bh[n], acc[m][n], 0, 0, 0);
                    acc[m][n] = __builtin_amdgcn_mfma_f32_16x16x32_bf16(ah[m], bl[n], acc[m][n], 0, 0, 0);
                    acc[m][n] = __builtin_amdgcn_mfma_f32_16x16x32_bf16(al[m], bh[n], acc[m][n], 0, 0, 0);
                }
            __syncthreads();
        }

#pragma unroll
        for (int m = 0; m < 2; ++m)
#pragma unroll
            for (int n = 0; n < 2; ++n)
#pragma unroll
                for (int q = 0; q < 4; ++q) {
                    int i = ti + wm * 32 + m * 16 + rh * 4 + q;
                    int j = tj + wn * 32 + n * 16 + rl;
                    size_t off = (size_t)i * N + j;
                    float v = acc[m][n][q] + 2.0f * DTf[off];   // (D^2)^T + 2 D^T
                    DTfn[off] = v;
                    ushort h, l;
                    split2(v, h, l);
                    *reinterpret_cast<ushort*>(DTnh + off) = h;
                    *reinterpret_cast<ushort*>(DTnl + off) = l;
                    size_t offT = (size_t)j * N + i;
                    *reinterpret_cast<ushort*>(Dnh + offT) = h;
                    *reinterpret_cast<ushort*>(Dnl + offT) = l;
                }
        return;
    }

    // ======== big path ========
    const long brow = (long)blockIdx.x * 128;
    const int bcol = blockIdx.y * 128;

    if (MODE == 0 && brow + 127 < (long)shift) {
        // fully below shift: Xo = Xi, float4 copy
#pragma unroll
        for (int j = 0; j < 16; ++j) {
            int c = j * 256 + tid;
            long off = (brow + (c >> 5)) * N + bcol + (c & 31) * 4;
            *(float4*)(Xo + off) = *(const float4*)(Xi + off);
        }
        return;
    }

    f32x4 acc[4][4];
#pragma unroll
    for (int m = 0; m < 4; ++m)
#pragma unroll
        for (int n = 0; n < 4; ++n) acc[m][n] = (f32x4){0.f, 0.f, 0.f, 0.f};

    // A staging (reg): chunk q: row=idx>>2, slot=idx&3; load linear slot, write swizzled
    int aoff[2]; const float* aptr[2]; bool avalid[2];
#pragma unroll
    for (int q = 0; q < 2; ++q) {
        int idx = q * 256 + tid;
        int row = idx >> 2, slot = idx & 3;
        aoff[q] = row * 64 + (slot ^ ((row >> 1) & 3)) * 16;
        long gr = brow + row - (MODE == 0 ? (long)shift : 0);
        avalid[q] = (gr >= 0);
        aptr[q] = Xi + gr * N + slot * 8;
    }
    // B staging (gload_lds): linear LDS dest, pre-swizzled global source
    const char* bptrh[2]; const char* bptrl[2];
#pragma unroll
    for (int q = 0; q < 2; ++q) {
        int idx = q * 256 + tid;
        int row = idx >> 2, slot = idx & 3;
        int sp = slot ^ ((row >> 1) & 3);
        bptrh[q] = (const char*)(Bph + (size_t)(bcol + row) * N + sp * 8);
        bptrl[q] = (NM == 3) ? (const char*)(Bpl + (size_t)(bcol + row) * N + sp * 8) : nullptr;
    }
    const int wqb = wave * 1024;

    f32x4 Ar[2][2][2];  // [set][chunk][2x float4] — static-indexed via full unroll
    auto loadA = [&](int t, int s) {
#pragma unroll
        for (int q = 0; q < 2; ++q) {
            if (avalid[q]) {
                Ar[s][q][0] = *reinterpret_cast<const f32x4*>(aptr[q] + t * 32);
                Ar[s][q][1] = *reinterpret_cast<const f32x4*>(aptr[q] + t * 32 + 4);
            } else {
                Ar[s][q][0] = (f32x4){0.f, 0.f, 0.f, 0.f};
                Ar[s][q][1] = (f32x4){0.f, 0.f, 0.f, 0.f};
            }
        }
    };
    auto writeA = [&](int s, char* buf) {
#pragma unroll
        for (int q = 0; q < 2; ++q) {
            float v[8];
            *reinterpret_cast<f32x4*>(&v[0]) = Ar[s][q][0];
            *reinterpret_cast<f32x4*>(&v[4]) = Ar[s][q][1];
            s16x8 h, l;
#pragma unroll
            for (int i = 0; i < 8; ++i) {
                ushort hh, ll;
                split2(v[i], hh, ll);
                h[i] = (short)hh; l[i] = (short)ll;
            }
            *reinterpret_cast<s16x8*>(buf + aoff[q]) = h;
            if (NM == 3) *reinterpret_cast<s16x8*>(buf + 8192 + aoff[q]) = l;
        }
    };
    auto gloadB = [&](int t, char* buf) {
#pragma unroll
        for (int q = 0; q < 2; ++q) {
            gload16(bptrh[q] + t * 64, buf + BH + q * 4096 + wqb);
            if (NM == 3) gload16(bptrl[q] + t * 64, buf + BH + 8192 + q * 4096 + wqb);
        }
    };

    // prologue
    loadA(0, 0);
    loadA(1, 1);
    gloadB(0, smem);
    writeA(0, smem);
    __syncthreads();

#pragma unroll
    for (int t = 0; t < 16; ++t) {
        char* bcur = smem + (t & 1) * LB;
        char* bnxt = smem + ((t + 1) & 1) * LB;
        if (t + 2 < 16) loadA(t + 2, t & 1);
        if (t + 1 < 16) gloadB(t + 1, bnxt);

        if constexpr (NM == 1) {
            s16x8 a[4], b[4];
#pragma unroll
            for (int m = 0; m < 4; ++m) {
                int row = wm * 64 + m * 16 + rl;
                a[m] = *reinterpret_cast<const s16x8*>(bcur + row * 64 + (rh ^ ((row >> 1) & 3)) * 16);
            }
#pragma unroll
            for (int n = 0; n < 4; ++n) {
                int row = wn * 64 + n * 16 + rl;
                b[n] = *reinterpret_cast<const s16x8*>(bcur + BH + row * 64 + (rh ^ ((row >> 1) & 3)) * 16);
            }
#pragma unroll
            for (int m = 0; m < 4; ++m)
#pragma unroll
                for (int n = 0; n < 4; ++n)
                    acc[m][n] = __builtin_amdgcn_mfma_f32_16x16x32_bf16(a[m], b[n], acc[m][n], 0, 0, 0);
        } else {
            s16x8 ah[4], al[4], bh[4], bl[4];
#pragma unroll
            for (int m = 0; m < 4; ++m) {
                int row = wm * 64 + m * 16 + rl;
                int off = row * 64 + (rh ^ ((row >> 1) & 3)) * 16;
                ah[m] = *reinterpret_cast<const s16x8*>(bcur + off);
                al[m] = *reinterpret_cast<const s16x8*>(bcur + 8192 + off);
            }
#pragma unroll
            for (int n = 0; n < 4; ++n) {
                int row = wn * 64 + n * 16 + rl;
                int off = row * 64 + (rh ^ ((row >> 1) & 3)) * 16;
                bh[n] = *reinterpret_cast<const s16x8*>(bcur + BH + off);
                bl[n] = *reinterpret_cast<const s16x8*>(bcur + BH + 8192 + off);
            }
#pragma unroll
            for (int m = 0; m < 4; ++m)
#pragma unroll
                for (int n = 0; n < 4; ++n) {
                    acc[m][n] = __builtin_amdgcn_mfma_f32_16x16x32_bf16(ah[m], bh[n], acc[m][n], 0, 0, 0);
                    acc[m][n] = __builtin_amdgcn_mfma_f32_16x16x32_bf16(ah[m], bl[n], acc[m][n], 0, 0, 0);
                    acc[m][n] = __builtin_amdgcn_mfma_f32_16x16x32_bf16(al[m], bh[n], acc[m][n], 0, 0, 0);
                }
        }
        if (t + 1 < 16) writeA((t + 1) & 1, bnxt);
        __syncthreads();
    }

    // epilogue: C/D layout col=lane&15, row=(lane>>4)*4+reg
    const long orow0 = brow + wm * 64;
    const int ocol0 = bcol + wn * 64;
#pragma unroll
    for (int m = 0; m < 4; ++m) {
#pragma unroll
        for (int q = 0; q < 4; ++q) {
            long gi = orow0 + m * 16 + rh * 4 + q;
            float* orow = Xo + gi * N + ocol0 + rl;
            if (MODE == 0) {
                const float* xr = Xi + gi * N + ocol0 + rl;
                const float* xs = xr - (long)shift * N;
                bool hasS = (gi >= (long)shift);
#pragma unroll
                for (int n = 0; n < 4; ++n) {
                    float v = acc[m][n][q] + xr[n * 16];
                    if (hasS) v += xs[n * 16];
                    orow[n * 16] = v;
                }
            } else {
#pragma unroll
                for (int n = 0; n < 4; ++n) orow[n * 16] = acc[m][n][q];
            }
        }
    }
}

// ---------------- launcher ----------------

extern "C" void kernel_launch(void* const* d_in, const int* in_sizes, int n_in,
                              void* d_out, int out_size, void* d_ws, size_t ws_size,
                              hipStream_t stream) {
    (void)in_sizes; (void)n_in; (void)out_size; (void)ws_size;
    const float* A = (const float*)d_in[0];
    const float* B = (const float*)d_in[1];
    const float* C = (const float*)d_in[2];
    const float* u = (const float*)d_in[3];

    const size_t NN = (size_t)N * N;
    const size_t LN = (size_t)L * N;

    float* X1 = (float*)d_out;   // ping buffer #2 (32 MB, overwritten by final GEMM)

    char* w = (char*)d_ws;
    float* X0 = (float*)w;     w += LN * 4;
    bf16 *Dh_[2], *Dl_[2], *DTh_[2], *DTl_[2];
    float* DTf_[2];
    for (int s = 0; s < 2; ++s) {
        Dh_[s]  = (bf16*)w;    w += NN * 2;
        Dl_[s]  = (bf16*)w;    w += NN * 2;
        DTh_[s] = (bf16*)w;    w += NN * 2;
        DTl_[s] = (bf16*)w;    w += NN * 2;
        DTf_[s] = (float*)w;   w += NN * 4;
    }
    float* M   = (float*)w;    w += NN * 4;
    float* MT  = (float*)w;    w += NN * 4;
    float* M2  = (float*)w;    w += NN * 4;
    float* BLm = (float*)w;    w += NN * 4;
    float* BT  = (float*)w;    w += NN * 4;
    float* Bbf = (float*)w;    w += NN * 4;
    float* D0f = (float*)w;    w += NN * 4;
    bf16* Bbh  = (bf16*)w;     w += NN * 2;
    bf16* Bbl  = (bf16*)w;     w += NN * 2;
    bf16* Ch   = (bf16*)w;     w += NN * 2;
    bf16* Cl   = (bf16*)w;     w += NN * 2;

    const float step = 1.0f / (float)L;

    dim3 b256(256);
    dim3 gEl((int)((NN + 255) / 256));
    dim3 bT(32, 8), gT(N / 32, N / 32);
    dim3 g64(N / 64, N / 64);
    dim3 gBig(L / 128, N / 128);
    dim3 gRound(L / 128 + 16, N / 128);   // + 64 sq blocks
    dim3 gS4n((int)(NN / 4 / 256));

    // ---- setup ----
    k_scale<<<gEl, b256, 0, stream>>>(A, M, step * 0.5f, (int)NN);
    k_transpose<<<gT, bT, 0, stream>>>(M, MT);
    k_qsq<<<g64, b256, 0, stream>>>(M, MT, M2, Bbh, Bbl, 1.0f);             // M2 = M@M (splits scratch)
    k_buildD<<<gEl, b256, 0, stream>>>(M, M2, D0f, Dh_[0], Dl_[0], BLm);    // D_0, BL
    k_tsplit<<<gT, bT, 0, stream>>>(D0f, DTf_[0], DTh_[0], DTl_[0]);        // D_0^T
    k_transpose<<<gT, bT, 0, stream>>>(B, BT);
    k_qsq<<<g64, b256, 0, stream>>>(BLm, BT, Bbf, Bbh, Bbl, step);          // Bb (+ split)
    k_split4<<<gS4n, b256, 0, stream>>>(C, Ch, Cl, (int)(NN / 4));

    // ---- Bu = u @ Bb^T -> X0 ----
    k_round<3, 1><<<gBig, b256, 0, stream>>>(
        u, X0, Bbh, Bbl, nullptr, nullptr, nullptr,
        nullptr, nullptr, nullptr, nullptr, nullptr, 0, 0);

    // ---- 14 doubling rounds (D_{r+1} squaring fused) ----
    for (int r = 0; r < 14; ++r) {
        int s = r & 1, nx = s ^ 1;
        float* Xi = (r & 1) ? X1 : X0;
        float* Xo = (r & 1) ? X0 : X1;
        int doSq = (r < 13) ? 1 : 0;
        if (r < 10)
            k_round<1, 0><<<gRound, b256, 0, stream>>>(
                Xi, Xo, Dh_[s], Dl_[s], DTh_[s], DTl_[s], DTf_[s],
                Dh_[nx], Dl_[nx], DTh_[nx], DTl_[nx], DTf_[nx], 1 << r, doSq);
        else
            k_round<3, 0><<<gRound, b256, 0, stream>>>(
                Xi, Xo, Dh_[s], Dl_[s], DTh_[s], DTl_[s], DTf_[s],
                Dh_[nx], Dl_[nx], DTh_[nx], DTl_[nx], DTf_[nx], 1 << r, doSq);
    }

    // ---- final: OUT = X0 @ C^T (f32, overwrites d_out) ----
    k_round<3, 1><<<gBig, b256, 0, stream>>>(
        X0, (float*)d_out, Ch, Cl, nullptr, nullptr, nullptr,
        nullptr, nullptr, nullptr, nullptr, nullptr, 0, 0);
}